// Round 19
// baseline (683.807 us; speedup 1.0000x reference)
//
#include <hip/hip_runtime.h>
#include <hip/hip_bf16.h>
#include <math.h>

typedef unsigned short u16;
typedef short s16x8 __attribute__((ext_vector_type(8)));
typedef float f32x4 __attribute__((ext_vector_type(4)));

#define BS_   32768      // B*S
#define SEQ_  4096
#define DM_   512
#define FF_   1024
#define FIN_  586
#define FINP_ 608        // emb K padded to 19*32
#define PADC  136        // epilogue LDS stride (u16), 128-wide tiles
#define PADB  520        // epilogue LDS stride (u16), 512-wide rows
#define NCH   8          // kv S-chunks

__device__ __forceinline__ u16 f2b(float f) {
    __hip_bfloat16 h = __float2bfloat16(f);      // RNE, hw v_cvt on gfx950
    return *reinterpret_cast<u16*>(&h);
}
__device__ __forceinline__ float b2f(u16 h) {
    union { unsigned u; float f; } a; a.u = ((unsigned)h) << 16;
    return a.f;
}

typedef __attribute__((address_space(1))) const unsigned gu32;
typedef __attribute__((address_space(3))) unsigned lu32;
__device__ __forceinline__ void glds16(const void* g, void* l) {
    __builtin_amdgcn_global_load_lds((gu32*)g, (lu32*)l, 16, 0, 0);
}

// ---------------- batched weight transpose + bf16 convert (one launch) ----------------
__device__ __forceinline__ void tr_tile(const float* __restrict__ W, u16* __restrict__ Wt,
                                        int K, int N, int Kpad, int tidx, int ktiles,
                                        float (*t)[33]) {
    int kb = (tidx % ktiles) << 5, nb = (tidx / ktiles) << 5;
    int tx = threadIdx.x, ty = threadIdx.y;          // 32 x 8
#pragma unroll
    for (int j = 0; j < 32; j += 8) {
        int k = kb + ty + j;
        t[ty + j][tx] = (k < K) ? W[(size_t)k * N + nb + tx] : 0.f;
    }
    __syncthreads();
#pragma unroll
    for (int j = 0; j < 32; j += 8) {
        Wt[(size_t)(nb + ty + j) * Kpad + kb + tx] = f2b(t[tx][ty + j]);
    }
}

__global__ void k_tr_all(const float* __restrict__ W0, const float* __restrict__ Wq,
                         const float* __restrict__ Wk, const float* __restrict__ Wv,
                         const float* __restrict__ Wo, const float* __restrict__ W1,
                         const float* __restrict__ W2,
                         u16* __restrict__ W0t, u16* __restrict__ Wqkv,
                         u16* __restrict__ Wot, u16* __restrict__ W1t,
                         u16* __restrict__ W2t) {
    __shared__ float t[32][33];
    int b = blockIdx.x;
    if (b < 304) { tr_tile(W0, W0t, FIN_, DM_, FINP_, b, 19, t); return; }   // 19x16 tiles
    b -= 304;
    int l = b >> 11;              // 2048 tiles per layer
    int r = b & 2047;
    if (r < 768) {                // q,k,v : 256 tiles each
        int sel = r >> 8, ti = r & 255;
        const float* src = sel == 0 ? Wq : (sel == 1 ? Wk : Wv);
        tr_tile(src + (size_t)l * 262144, Wqkv + (size_t)l * 786432 + (size_t)sel * 262144,
                512, 512, 512, ti, 16, t);
    } else if (r < 1024) {
        tr_tile(Wo + (size_t)l * 262144, Wot + (size_t)l * 262144, 512, 512, 512, r - 768, 16, t);
    } else if (r < 1536) {
        tr_tile(W1 + (size_t)l * 524288, W1t + (size_t)l * 524288, 512, 1024, 512, r - 1024, 16, t);
    } else {
        tr_tile(W2 + (size_t)l * 524288, W2t + (size_t)l * 524288, 1024, 512, 1024, r - 1536, 32, t);
    }
}

// ---------------- embeddings -> bf16 padded [BS][608] ---------------------------------
__global__ __launch_bounds__(256)
void k_emb(const float* __restrict__ E, u16* __restrict__ Ep) {
    const int total8 = BS_ * (FINP_ / 8);
    for (int i = blockIdx.x * 256 + threadIdx.x; i < total8; i += gridDim.x * 256) {
        int rr = i / (FINP_ / 8), c = (i % (FINP_ / 8)) * 8;
        const float* rp = E + (size_t)rr * FIN_ + c;
        s16x8 o;
#pragma unroll
        for (int e = 0; e < 8; ++e) {
            float v = (c + e < FIN_) ? rp[e] : 0.f;
            o[e] = (short)f2b(v);
        }
        *(s16x8*)(Ep + (size_t)rr * FINP_ + c) = o;
    }
}

// ---------------- MFMA GEMM: barrier-free wave-autonomous K-loop ----------------------
// 128x128 tile, 4 waves, each wave stages its OWN 8KB LDS slice (A 64x32 + B 64x32)
// via per-wave glds + per-wave s_waitcnt vmcnt(0). NO __syncthreads in the K-loop ->
// 16 waves/CU fully decoupled pipelines (TLP hides L2 latency; MFMA pipe time-shared).
// A/B staged 2x per block (L2 absorbs). 8-slot swizzle: source chunk (l&3)^((l>>3)&3),
// read slot lg^((lr>>1)&3). WAR-safe: glds(t+1) issued after lgkm-waited MFMAs(t);
// sched_barrier(0) fences compiler reordering.
// EPI: 0 = bias only, 1 = QKV split (feat on q,k), 3 = relu
template<int EPI>
__global__ __launch_bounds__(256, 4)
void k_gemm(const u16* __restrict__ A, const u16* __restrict__ Bt,
            const float* __restrict__ bias0, const float* __restrict__ bias1,
            const float* __restrict__ bias2,
            u16* __restrict__ out0, u16* __restrict__ out1, u16* __restrict__ out2,
            int M, int N, int K, int NT) {
    __shared__ __align__(16) u16 smem[16384];      // 32 KB: 4 waves x 8KB; sC unions in
    u16* sC = smem;

    const int nwg = gridDim.x;
    const int cpx = nwg >> 3;                      // nwg % 8 == 0 for all launches here
    const int wg = (blockIdx.x & 7) * cpx + (blockIdx.x >> 3);
    const int mt = wg / NT, nt = wg - mt * NT;
    const int m0 = mt << 7, n0 = nt << 7;
    const int tid = threadIdx.x;
    const int w = tid >> 6, l = tid & 63;
    const int wm = (w >> 1) << 6, wn = (w & 1) << 6;
    const int lr = l & 15, lg = l >> 4;

    // per-wave private LDS slice
    u16* wA = smem + w * 4096;                     // [64][32]
    u16* wB = wA + 2048;                           // [64][32]

    // per-wave staging: glds g covers rows g*16 + (l>>2), chunk l&3 (source-swizzled)
    const int srcswz = (((l & 3) ^ ((l >> 3) & 3)) & 3) << 3;
    const u16* Awp = A + (size_t)(m0 + wm + (l >> 2)) * K + srcswz;
    const u16* Bwp = Bt + (size_t)(n0 + wn + (l >> 2)) * K + srcswz;

    const int axk = ((lg ^ ((lr >> 1) & 3)) & 3) << 3;   // read-side swizzle

    f32x4 acc[4][4] = {};
    const int ntile = K >> 5;

    for (int t = 0; t < ntile; ++t) {
        const size_t ko = (size_t)t << 5;
#pragma unroll
        for (int g = 0; g < 4; ++g) {
            glds16(Awp + ko + (size_t)(g * 16) * K, wA + g * 512 + l * 8);
            glds16(Bwp + ko + (size_t)(g * 16) * K, wB + g * 512 + l * 8);
        }
        asm volatile("s_waitcnt vmcnt(0)" ::: "memory");
        __builtin_amdgcn_sched_barrier(0);
        s16x8 af[4], bfr[4];
#pragma unroll
        for (int i = 0; i < 4; ++i) af[i] = *(const s16x8*)(wA + (i * 16 + lr) * 32 + axk);
#pragma unroll
        for (int j = 0; j < 4; ++j) bfr[j] = *(const s16x8*)(wB + (j * 16 + lr) * 32 + axk);
        __builtin_amdgcn_s_setprio(1);
#pragma unroll
        for (int i = 0; i < 4; ++i)
#pragma unroll
            for (int j = 0; j < 4; ++j)
                acc[i][j] = __builtin_amdgcn_mfma_f32_16x16x32_bf16(af[i], bfr[j], acc[i][j], 0, 0, 0);
        __builtin_amdgcn_s_setprio(0);
        __builtin_amdgcn_sched_barrier(0);         // keep next glds below MFMAs (LDS WAR)
    }
    __syncthreads();                               // converge before sC reuse

    const int seg = (EPI == 1) ? (n0 >> 9) : 0;
    const float* bias = (EPI == 1) ? (seg == 0 ? bias0 : (seg == 1 ? bias1 : bias2)) : bias0;
    u16* dst = (EPI == 1) ? (seg == 0 ? out0 : (seg == 1 ? out1 : out2)) : out0;
    const int ldo = (EPI == 1) ? 512 : N;
    const int ncol0 = (EPI == 1) ? (n0 & 511) : n0;

#pragma unroll
    for (int pass = 0; pass < 2; ++pass) {
        if ((w >> 1) == pass) {
#pragma unroll
            for (int j = 0; j < 4; ++j) {
                const int col = wn + j * 16 + lr;
                const float bv = bias[ncol0 + col];
#pragma unroll
                for (int i = 0; i < 4; ++i)
#pragma unroll
                    for (int r = 0; r < 4; ++r) {
                        const int row = i * 16 + (lg << 2) + r;
                        sC[row * PADC + col] = f2b(acc[i][j][r] + bv);
                    }
            }
        }
        __syncthreads();
        const int rbase = m0 + (pass << 6);
#pragma unroll
        for (int t = 0; t < 4; ++t) {
            const int idx = t * 256 + tid;
            const int row = idx >> 4;
            const int c8 = (idx & 15) << 3;
            s16x8 v8 = *(const s16x8*)(sC + row * PADC + c8);
            size_t gaddr = (size_t)(rbase + row) * ldo + ncol0 + c8;
            s16x8 o = v8;
            if constexpr (EPI == 1) {
                if (seg < 2) {
#pragma unroll
                    for (int e = 0; e < 8; ++e) {
                        float v = b2f((u16)v8[e]);
                        v = (v > 0.f) ? v + 1.f : __expf(v);   // elu+1
                        o[e] = (short)f2b(v);
                    }
                }
            } else if constexpr (EPI == 3) {
#pragma unroll
                for (int e = 0; e < 8; ++e)
                    o[e] = (short)f2b(fmaxf(b2f((u16)v8[e]), 0.f));
            }
            *(s16x8*)(dst + gaddr) = o;
        }
        __syncthreads();
    }
}

// ---------------- row-tile GEMM + residual + LayerNorm fused --------------------------
template<int K>
__global__ __launch_bounds__(512, 4)
void k_gemm_ln(const u16* __restrict__ A, const u16* __restrict__ Bt,
               const float* __restrict__ bias, const u16* __restrict__ resid,
               const float* __restrict__ g, const float* __restrict__ be,
               u16* __restrict__ xb) {
    __shared__ __align__(16) u16 smem[36864];      // 72 KB; sC[64][PADB] unions in
    u16* sC = smem;

    const int nwg = gridDim.x;
    const int cpx = nwg >> 3;
    const int wg = (blockIdx.x & 7) * cpx + (blockIdx.x >> 3);
    const int m0 = wg << 6;                        // 64 rows per block, N = 512 full
    const int tid = threadIdx.x;
    const int w = tid >> 6, l = tid & 63;
    const int wn = w << 6;
    const int lr = l & 15, lg = l >> 4;

    const int srow = tid >> 2;                     // 0..127
    const int swz = (((tid & 3) ^ ((srow >> 1) & 3)) & 3) << 3;
    const u16* ApA = A + (size_t)(m0 + (srow & 63)) * K + ((((tid & 3) ^ (((srow & 63) >> 1) & 3)) & 3) << 3);
    const u16* BpB = Bt + (size_t)srow * K + swz;

    auto stage = [&](int d, int tt) {
        const size_t ko = (size_t)tt << 5;
        if (tid < 256) glds16(ApA + ko, smem + d * 2048 + tid * 8);
#pragma unroll
        for (int c = 0; c < 4; ++c)
            glds16(BpB + ko + (size_t)(c * 128) * K,
                   smem + 4096 + d * 16384 + c * 4096 + tid * 8);
    };

    const int axk = ((lg ^ ((lr >> 1) & 3)) & 3) << 3;

    f32x4 acc[4][4] = {};
    const int ntile = K >> 5;

    stage(0, 0);
    __syncthreads();

    for (int t = 0; t < ntile; ++t) {
        const int d = t & 1;
        if (t + 1 < ntile) stage(d ^ 1, t + 1);
        const u16* sA = smem + d * 2048;
        const u16* sB = smem + 4096 + d * 16384 + wn * 32;
        s16x8 af[4], bfr[4];
#pragma unroll
        for (int i = 0; i < 4; ++i) af[i] = *(const s16x8*)(sA + (i * 16 + lr) * 32 + axk);
#pragma unroll
        for (int j = 0; j < 4; ++j) bfr[j] = *(const s16x8*)(sB + (j * 16 + lr) * 32 + axk);
        __builtin_amdgcn_s_setprio(1);
#pragma unroll
        for (int i = 0; i < 4; ++i)
#pragma unroll
            for (int j = 0; j < 4; ++j)
                acc[i][j] = __builtin_amdgcn_mfma_f32_16x16x32_bf16(af[i], bfr[j], acc[i][j], 0, 0, 0);
        __builtin_amdgcn_s_setprio(0);
        __syncthreads();
    }

#pragma unroll
    for (int j = 0; j < 4; ++j) {
        const int col = wn + j * 16 + lr;
        const float bv = bias[col];
#pragma unroll
        for (int i = 0; i < 4; ++i)
#pragma unroll
            for (int r = 0; r < 4; ++r) {
                const int row = i * 16 + (lg << 2) + r;     // 0..63
                sC[row * PADB + col] = f2b(acc[i][j][r] + bv);
            }
    }
    __syncthreads();

#pragma unroll
    for (int it = 0; it < 8; ++it) {
        const int row = it * 8 + w;                 // 0..63
        s16x8 cv = *(const s16x8*)(sC + row * PADB + l * 8);
        s16x8 rv = *(const s16x8*)(resid + (size_t)(m0 + row) * DM_ + l * 8);
        float x[8];
#pragma unroll
        for (int e = 0; e < 8; ++e) x[e] = b2f((u16)cv[e]) + b2f((u16)rv[e]);
        float sum = 0.f;
#pragma unroll
        for (int e = 0; e < 8; ++e) sum += x[e];
#pragma unroll
        for (int off = 32; off > 0; off >>= 1) sum += __shfl_xor(sum, off);
        float mu = sum * (1.f / DM_);
        float sq = 0.f;
#pragma unroll
        for (int e = 0; e < 8; ++e) { float d = x[e] - mu; sq += d * d; }
#pragma unroll
        for (int off = 32; off > 0; off >>= 1) sq += __shfl_xor(sq, off);
        float rs = rsqrtf(sq * (1.f / DM_) + 1e-5f);
        const int c = l * 8;
        const f32x4* gp = (const f32x4*)(g + c);
        const f32x4* bp = (const f32x4*)(be + c);
        f32x4 g0 = gp[0], g1 = gp[1], e0 = bp[0], e1 = bp[1];
        s16x8 pk;
#pragma unroll
        for (int e = 0; e < 4; ++e) pk[e] = (short)f2b((x[e] - mu) * rs * g0[e] + e0[e]);
#pragma unroll
        for (int e = 0; e < 4; ++e) pk[4 + e] = (short)f2b((x[4 + e] - mu) * rs * g1[e] + e1[e]);
        *(s16x8*)(xb + (size_t)(m0 + row) * DM_ + c) = pk;
    }
}

// ---------------- kv einsum partials ---------------------------------------------------
__global__ __launch_bounds__(256)
void k_kv(const u16* __restrict__ kb_, const u16* __restrict__ vb_,
          float* __restrict__ kvp, float* __restrict__ ksump) {
    __shared__ float sk[64 * 68], sv[64 * 68];
    int bh = blockIdx.x, b = bh >> 3, h = bh & 7;
    int ch = blockIdx.y;
    int tid = threadIdx.x;
    int d0 = (tid & 15) << 2, m0 = (tid >> 4) << 2;
    float acc[4][4] = {};
    float ks[4] = {0.f, 0.f, 0.f, 0.f};
    size_t gbase = ((size_t)b * SEQ_ + (size_t)ch * (SEQ_ / NCH)) * DM_ + h * 64;

    for (int st = 0; st < SEQ_ / NCH; st += 64) {
#pragma unroll
        for (int i = 0; i < 2; ++i) {
            int li = tid + (i << 8);
            int r = li >> 3, c8 = (li & 7) << 3;
            s16x8 kv_ = *(const s16x8*)(kb_ + gbase + (size_t)(st + r) * DM_ + c8);
            s16x8 vv_ = *(const s16x8*)(vb_ + gbase + (size_t)(st + r) * DM_ + c8);
#pragma unroll
            for (int e = 0; e < 8; ++e) {
                sk[r * 68 + c8 + e] = b2f((u16)kv_[e]);
                sv[r * 68 + c8 + e] = b2f((u16)vv_[e]);
            }
        }
        __syncthreads();
        for (int s = 0; s < 64; ++s) {
            f32x4 kd = *(const f32x4*)(sk + s * 68 + d0);
            f32x4 vm = *(const f32x4*)(sv + s * 68 + m0);
#pragma unroll
            for (int i = 0; i < 4; ++i)
#pragma unroll
                for (int j = 0; j < 4; ++j) acc[i][j] += kd[i] * vm[j];
            if ((tid >> 4) == 0) { ks[0] += kd[0]; ks[1] += kd[1]; ks[2] += kd[2]; ks[3] += kd[3]; }
        }
        __syncthreads();
    }
    float* kvo = kvp + ((size_t)ch * 64 + bh) * 4096;
#pragma unroll
    for (int i = 0; i < 4; ++i)
#pragma unroll
        for (int j = 0; j < 4; ++j) kvo[(d0 + i) * 64 + m0 + j] = acc[i][j];
    if ((tid >> 4) == 0) {
        float* kso = ksump + ((size_t)ch * 64 + bh) * 64;
#pragma unroll
        for (int e = 0; e < 4; ++e) kso[d0 + e] = ks[e];
    }
}

// ---------------- reduce partials once: kvt bf16 [bh][m][d swizzled] + ksum f32 -------
__global__ __launch_bounds__(256)
void k_red(const float* __restrict__ kvp, const float* __restrict__ ksump,
           u16* __restrict__ kvt, float* __restrict__ ksum) {
    int bh = blockIdx.x, q = blockIdx.y;           // q in 0..3
    int tid = threadIdx.x;
#pragma unroll
    for (int p = 0; p < 4; ++p) {
        int i = (q * 4 + p) * 256 + tid;           // i = d*64 + m
        float v = 0.f;
#pragma unroll
        for (int c = 0; c < NCH; ++c) v += kvp[((size_t)c * 64 + bh) * 4096 + i];
        int d = i >> 6, m = i & 63;
        int slot = ((d >> 3) ^ (m & 7)) & 7;
        kvt[(size_t)bh * 4096 + m * 64 + slot * 8 + (d & 7)] = f2b(v);
    }
    if (q == 0 && tid < 64) {
        float v = 0.f;
#pragma unroll
        for (int c = 0; c < NCH; ++c) v += ksump[((size_t)c * 64 + bh) * 64 + tid];
        ksum[bh * 64 + tid] = v;
    }
}

// ---------------- attention apply via MFMA: a = (q . kv) * z --------------------------
__global__ __launch_bounds__(256)
void k_attn(const u16* __restrict__ qb_, const u16* __restrict__ kvt,
            const float* __restrict__ ksum, u16* __restrict__ ab_) {
    __shared__ __align__(16) u16 qs[256 * 64];     // 32KB (reused as output bounce)
    __shared__ __align__(16) u16 skv[64 * 64];     // 8KB
    __shared__ float sden[256];
    __shared__ float sks[64];
    const int tid = threadIdx.x;
    const int bh = blockIdx.y, b = bh >> 3, h = bh & 7;
    const int s0 = blockIdx.x << 8;                // 256 rows
    const int w = tid >> 6, l = tid & 63;
    const int lr = l & 15, lg = l >> 4;

    {
        const int srw = tid >> 3, ch = tid & 7;
        const int scol = ((ch ^ (srw & 7)) & 7) << 3;
        const u16* qsrc = qb_ + ((size_t)b * SEQ_ + s0 + srw) * DM_ + h * 64 + scol;
#pragma unroll
        for (int p = 0; p < 8; ++p)
            glds16(qsrc + (size_t)(p * 32) * DM_, qs + p * 2048 + tid * 8);
#pragma unroll
        for (int p = 0; p < 2; ++p)
            glds16(kvt + (size_t)bh * 4096 + p * 2048 + tid * 8, skv + p * 2048 + tid * 8);
    }
    if (tid < 64) sks[tid] = ksum[bh * 64 + tid];
    __syncthreads();

    {
        const int row = (w << 6) + l;
        float den = 0.f;
#pragma unroll
        for (int c = 0; c < 8; ++c) {
            s16x8 qv = *(const s16x8*)(qs + row * 64 + (((c ^ (row & 7)) & 7) << 3));
#pragma unroll
            for (int e = 0; e < 8; ++e) den += b2f((u16)qv[e]) * sks[c * 8 + e];
        }
        sden[row] = 1.f / (den + 1e-6f);
    }
    __syncthreads();

    f32x4 acc[4][4] = {};
#pragma unroll
    for (int kh = 0; kh < 2; ++kh) {
        const int c = kh * 4 + lg;
        s16x8 bfr[4];
#pragma unroll
        for (int j = 0; j < 4; ++j) {
            const int mm = j * 16 + lr;
            bfr[j] = *(const s16x8*)(skv + mm * 64 + (((c ^ (mm & 7)) & 7) << 3));
        }
#pragma unroll
        for (int i = 0; i < 4; ++i) {
            const int rr = (w << 6) + i * 16 + lr;
            s16x8 af = *(const s16x8*)(qs + rr * 64 + (((c ^ (rr & 7)) & 7) << 3));
#pragma unroll
            for (int j = 0; j < 4; ++j)
                acc[i][j] = __builtin_amdgcn_mfma_f32_16x16x32_bf16(af, bfr[j], acc[i][j], 0, 0, 0);
        }
    }
    __syncthreads();                               // all qs reads done; reuse as bounce

#pragma unroll
    for (int i = 0; i < 4; ++i) {
#pragma unroll
        for (int r = 0; r < 4; ++r) {
            const int row = (w << 6) + i * 16 + (lg << 2) + r;
            const float z = sden[row];
#pragma unroll
            for (int j = 0; j < 4; ++j)
                qs[row * 64 + j * 16 + lr] = f2b(acc[i][j][r] * z);
        }
    }
    __syncthreads();
    {
        const int srw = tid >> 3, ch = tid & 7;
        u16* odst = ab_ + ((size_t)b * SEQ_ + s0 + srw) * DM_ + h * 64 + ch * 8;
#pragma unroll
        for (int p = 0; p < 8; ++p)
            *(s16x8*)(odst + (size_t)(p * 32) * DM_) = *(const s16x8*)(qs + p * 2048 + tid * 8);
    }
}

// ---------------- final LN + Wout dot (bf16 in) ----------------------------------------
__global__ __launch_bounds__(256)
void k_final(const u16* __restrict__ in, const float* __restrict__ gf,
             const float* __restrict__ bf_, const float* __restrict__ wout,
             const float* __restrict__ bout, float* __restrict__ out) {
    int row = blockIdx.x * 4 + (threadIdx.x >> 6);
    int l = threadIdx.x & 63;
    s16x8 raw = *(const s16x8*)(in + (size_t)row * DM_ + l * 8);
    float x[8];
#pragma unroll
    for (int e = 0; e < 8; ++e) x[e] = b2f((u16)raw[e]);
    float sum = 0.f;
#pragma unroll
    for (int e = 0; e < 8; ++e) sum += x[e];
#pragma unroll
    for (int off = 32; off > 0; off >>= 1) sum += __shfl_xor(sum, off);
    float mu = sum * (1.f / DM_);
    float sq = 0.f;
#pragma unroll
    for (int e = 0; e < 8; ++e) { float d = x[e] - mu; sq += d * d; }
#pragma unroll
    for (int off = 32; off > 0; off >>= 1) sq += __shfl_xor(sq, off);
    float rs = rsqrtf(sq * (1.f / DM_) + 1e-5f);
    int c = l * 8;
    float p = 0.f;
#pragma unroll
    for (int e = 0; e < 8; ++e)
        p += ((x[e] - mu) * rs * gf[c + e] + bf_[c + e]) * wout[c + e];
#pragma unroll
    for (int off = 32; off > 0; off >>= 1) p += __shfl_xor(p, off);
    if (l == 0) out[row] = p + bout[0];
}

// =======================================================================================
extern "C" void kernel_launch(void* const* d_in, const int* in_sizes, int n_in,
                              void* d_out, int out_size, void* d_ws, size_t ws_size,
                              hipStream_t stream) {
    const float* emb   = (const float*)d_in[0];
    const float* W0    = (const float*)d_in[1];
    const float* b0    = (const float*)d_in[2];
    const float* Wq    = (const float*)d_in[3];
    const float* bq    = (const float*)d_in[4];
    const float* Wk    = (const float*)d_in[5];
    const float* bk    = (const float*)d_in[6];
    const float* Wv    = (const float*)d_in[7];
    const float* bv    = (const float*)d_in[8];
    const float* Wo    = (const float*)d_in[9];
    const float* bo    = (const float*)d_in[10];
    const float* ln1s  = (const float*)d_in[11];
    const float* ln1b  = (const float*)d_in[12];
    const float* W1    = (const float*)d_in[13];
    const float* b1    = (const float*)d_in[14];
    const float* W2    = (const float*)d_in[15];
    const float* b2    = (const float*)d_in[16];
    const float* ln2s  = (const float*)d_in[17];
    const float* ln2b  = (const float*)d_in[18];
    const float* lnfs  = (const float*)d_in[19];
    const float* lnfb  = (const float*)d_in[20];
    const float* Wout  = (const float*)d_in[21];
    const float* bout  = (const float*)d_in[22];
    float* out = (float*)d_out;

    char* ws = (char*)d_ws;
    size_t off = 0;
    auto alloc = [&](size_t bytes) -> void* {
        void* p = ws + off;
        off += (bytes + 255) & ~(size_t)255;
        return p;
    };
    u16* xb   = (u16*)alloc((size_t)BS_ * DM_ * 2);    // 32MB  x (bf16 stream)
    u16* qb   = (u16*)alloc((size_t)BS_ * DM_ * 2);    // 32MB
    u16* kb   = (u16*)alloc((size_t)BS_ * DM_ * 2);    // 32MB
    u16* vb   = (u16*)alloc((size_t)BS_ * DM_ * 2);    // 32MB
    float* kvp   = (float*)alloc((size_t)NCH * 64 * 4096 * 4);   // 8MB
    float* ksump = (float*)alloc((size_t)NCH * 64 * 64 * 4);
    u16* kvt  = (u16*)alloc((size_t)64 * 4096 * 2);    // 512KB
    float* ksum = (float*)alloc((size_t)64 * 64 * 4);
    u16* wp   = (u16*)alloc((size_t)4521984 * 2);      // weight pool ~9MB

    u16* ab   = vb;    // attn output (written after vb consumed)
    u16* h1b  = kb;    // 64MB FF hidden = kb+vb regions
    u16* embp = kb;    // 38MB emb bf16 padded = kb+vb regions (dead before QKV)

    u16* W0t  = wp;                          // [512][608]
    u16* Wqkv = wp + 311296;                 // per layer [1536][512]
    u16* Wot  = Wqkv + 2 * 786432;           // per layer [512][512]
    u16* W1t  = Wot + 2 * 262144;            // per layer [1024][512]
    u16* W2t  = W1t + 2 * 524288;            // per layer [512][1024]

    k_tr_all<<<4400, dim3(32, 8), 0, stream>>>(W0, Wq, Wk, Wv, Wo, W1, W2,
                                               W0t, Wqkv, Wot, W1t, W2t);
    k_emb<<<2560, 256, 0, stream>>>(emb, embp);

    // x = emb @ W0 + b0
    k_gemm<0><<<1024, 256, 0, stream>>>(embp, W0t, b0, nullptr, nullptr,
                                        xb, nullptr, nullptr, BS_, DM_, FINP_, 4);

    for (int l = 0; l < 2; ++l) {
        // fused QKV: N=1536, feat(elu+1) on q,k
        k_gemm<1><<<3072, 256, 0, stream>>>(xb, Wqkv + (size_t)l * 786432,
                                            bq + l * 512, bk + l * 512, bv + l * 512,
                                            qb, kb, vb, BS_, 1536, 512, 12);
        k_kv<<<dim3(64, NCH), 256, 0, stream>>>(kb, vb, kvp, ksump);
        k_red<<<dim3(64, 4), 256, 0, stream>>>(kvp, ksump, kvt, ksum);
        k_attn<<<dim3(16, 64), 256, 0, stream>>>(qb, kvt, ksum, ab);
        // x = LN1(x + a@Wo + bo)   (fused: GEMM + resid + LN)
        k_gemm_ln<512><<<512, 512, 0, stream>>>(ab, Wot + (size_t)l * 262144,
                                                bo + l * 512, xb,
                                                ln1s + l * 512, ln1b + l * 512, xb);
        // h = relu(x@W1+b1)
        k_gemm<3><<<2048, 256, 0, stream>>>(xb, W1t + (size_t)l * 524288,
                                            b1 + l * 1024, nullptr, nullptr,
                                            h1b, nullptr, nullptr, BS_, 1024, 512, 8);
        // x = LN2(x + h@W2 + b2)   (fused)
        k_gemm_ln<1024><<<512, 512, 0, stream>>>(h1b, W2t + (size_t)l * 524288,
                                                 b2 + l * 512, xb,
                                                 ln2s + l * 512, ln2b + l * 512, xb);
    }
    k_final<<<8192, 256, 0, stream>>>(xb, lnfs, lnfb, Wout, bout, out);
}

// Round 20
// 678.179 us; speedup vs baseline: 1.0083x; 1.0083x over previous
//
#include <hip/hip_runtime.h>
#include <hip/hip_bf16.h>
#include <math.h>

typedef unsigned short u16;
typedef short s16x8 __attribute__((ext_vector_type(8)));
typedef float f32x4 __attribute__((ext_vector_type(4)));

#define BS_   32768      // B*S
#define SEQ_  4096
#define DM_   512
#define FF_   1024
#define FIN_  586
#define FINP_ 608        // emb K padded to 19*32
#define PADC  136        // epilogue LDS stride (u16), 128-wide tiles
#define PADB  520        // epilogue LDS stride (u16), 512-wide rows
#define NCH   8          // kv S-chunks

__device__ __forceinline__ u16 f2b(float f) {
    __hip_bfloat16 h = __float2bfloat16(f);      // RNE, hw v_cvt on gfx950
    return *reinterpret_cast<u16*>(&h);
}
__device__ __forceinline__ float b2f(u16 h) {
    union { unsigned u; float f; } a; a.u = ((unsigned)h) << 16;
    return a.f;
}

typedef __attribute__((address_space(1))) const unsigned gu32;
typedef __attribute__((address_space(3))) unsigned lu32;
__device__ __forceinline__ void glds16(const void* g, void* l) {
    __builtin_amdgcn_global_load_lds((gu32*)g, (lu32*)l, 16, 0, 0);
}

// ---------------- batched weight transpose + bf16 convert (one launch) ----------------
__device__ __forceinline__ void tr_tile(const float* __restrict__ W, u16* __restrict__ Wt,
                                        int K, int N, int Kpad, int tidx, int ktiles,
                                        float (*t)[33]) {
    int kb = (tidx % ktiles) << 5, nb = (tidx / ktiles) << 5;
    int tx = threadIdx.x, ty = threadIdx.y;          // 32 x 8
#pragma unroll
    for (int j = 0; j < 32; j += 8) {
        int k = kb + ty + j;
        t[ty + j][tx] = (k < K) ? W[(size_t)k * N + nb + tx] : 0.f;
    }
    __syncthreads();
#pragma unroll
    for (int j = 0; j < 32; j += 8) {
        Wt[(size_t)(nb + ty + j) * Kpad + kb + tx] = f2b(t[tx][ty + j]);
    }
}

__global__ void k_tr_all(const float* __restrict__ W0, const float* __restrict__ Wq,
                         const float* __restrict__ Wk, const float* __restrict__ Wv,
                         const float* __restrict__ Wo, const float* __restrict__ W1,
                         const float* __restrict__ W2,
                         u16* __restrict__ W0t, u16* __restrict__ Wqkv,
                         u16* __restrict__ Wot, u16* __restrict__ W1t,
                         u16* __restrict__ W2t) {
    __shared__ float t[32][33];
    int b = blockIdx.x;
    if (b < 304) { tr_tile(W0, W0t, FIN_, DM_, FINP_, b, 19, t); return; }   // 19x16 tiles
    b -= 304;
    int l = b >> 11;              // 2048 tiles per layer
    int r = b & 2047;
    if (r < 768) {                // q,k,v : 256 tiles each
        int sel = r >> 8, ti = r & 255;
        const float* src = sel == 0 ? Wq : (sel == 1 ? Wk : Wv);
        tr_tile(src + (size_t)l * 262144, Wqkv + (size_t)l * 786432 + (size_t)sel * 262144,
                512, 512, 512, ti, 16, t);
    } else if (r < 1024) {
        tr_tile(Wo + (size_t)l * 262144, Wot + (size_t)l * 262144, 512, 512, 512, r - 768, 16, t);
    } else if (r < 1536) {
        tr_tile(W1 + (size_t)l * 524288, W1t + (size_t)l * 524288, 512, 1024, 512, r - 1024, 16, t);
    } else {
        tr_tile(W2 + (size_t)l * 524288, W2t + (size_t)l * 524288, 1024, 512, 1024, r - 1536, 32, t);
    }
}

// ---------------- embeddings -> bf16 padded [BS][608] ---------------------------------
__global__ __launch_bounds__(256)
void k_emb(const float* __restrict__ E, u16* __restrict__ Ep) {
    const int total8 = BS_ * (FINP_ / 8);
    for (int i = blockIdx.x * 256 + threadIdx.x; i < total8; i += gridDim.x * 256) {
        int rr = i / (FINP_ / 8), c = (i % (FINP_ / 8)) * 8;
        const float* rp = E + (size_t)rr * FIN_ + c;
        s16x8 o;
#pragma unroll
        for (int e = 0; e < 8; ++e) {
            float v = (c + e < FIN_) ? rp[e] : 0.f;
            o[e] = (short)f2b(v);
        }
        *(s16x8*)(Ep + (size_t)rr * FINP_ + c) = o;
    }
}

// ---------------- MFMA GEMM: barrier-free wave-autonomous K-loop ----------------------
// 128x128 tile, 4 waves, each wave stages its OWN 8KB LDS slice (A 64x32 + B 64x32)
// via per-wave glds + per-wave s_waitcnt vmcnt(0). NO __syncthreads in the K-loop ->
// 16 waves/CU fully decoupled pipelines (TLP hides L2 latency; MFMA pipe time-shared).
// A/B staged 2x per block (L2 absorbs). 8-slot swizzle: source chunk (l&3)^((l>>3)&3),
// read slot lg^((lr>>1)&3). WAR-safe: glds(t+1) issued after lgkm-waited MFMAs(t);
// sched_barrier(0) fences compiler reordering.
// EPI: 0 = bias only, 1 = QKV split (feat on q,k), 3 = relu
template<int EPI>
__global__ __launch_bounds__(256, 4)
void k_gemm(const u16* __restrict__ A, const u16* __restrict__ Bt,
            const float* __restrict__ bias0, const float* __restrict__ bias1,
            const float* __restrict__ bias2,
            u16* __restrict__ out0, u16* __restrict__ out1, u16* __restrict__ out2,
            int M, int N, int K, int NT) {
    __shared__ __align__(16) u16 smem[16384];      // 32 KB: 4 waves x 8KB; sC unions in
    u16* sC = smem;

    const int nwg = gridDim.x;
    const int cpx = nwg >> 3;                      // nwg % 8 == 0 for all launches here
    const int wg = (blockIdx.x & 7) * cpx + (blockIdx.x >> 3);
    const int mt = wg / NT, nt = wg - mt * NT;
    const int m0 = mt << 7, n0 = nt << 7;
    const int tid = threadIdx.x;
    const int w = tid >> 6, l = tid & 63;
    const int wm = (w >> 1) << 6, wn = (w & 1) << 6;
    const int lr = l & 15, lg = l >> 4;

    // per-wave private LDS slice
    u16* wA = smem + w * 4096;                     // [64][32]
    u16* wB = wA + 2048;                           // [64][32]

    // per-wave staging: glds g covers rows g*16 + (l>>2), chunk l&3 (source-swizzled)
    const int srcswz = (((l & 3) ^ ((l >> 3) & 3)) & 3) << 3;
    const u16* Awp = A + (size_t)(m0 + wm + (l >> 2)) * K + srcswz;
    const u16* Bwp = Bt + (size_t)(n0 + wn + (l >> 2)) * K + srcswz;

    const int axk = ((lg ^ ((lr >> 1) & 3)) & 3) << 3;   // read-side swizzle

    f32x4 acc[4][4] = {};
    const int ntile = K >> 5;

    for (int t = 0; t < ntile; ++t) {
        const size_t ko = (size_t)t << 5;
#pragma unroll
        for (int g = 0; g < 4; ++g) {
            glds16(Awp + ko + (size_t)(g * 16) * K, wA + g * 512 + l * 8);
            glds16(Bwp + ko + (size_t)(g * 16) * K, wB + g * 512 + l * 8);
        }
        asm volatile("s_waitcnt vmcnt(0)" ::: "memory");
        __builtin_amdgcn_sched_barrier(0);
        s16x8 af[4], bfr[4];
#pragma unroll
        for (int i = 0; i < 4; ++i) af[i] = *(const s16x8*)(wA + (i * 16 + lr) * 32 + axk);
#pragma unroll
        for (int j = 0; j < 4; ++j) bfr[j] = *(const s16x8*)(wB + (j * 16 + lr) * 32 + axk);
        __builtin_amdgcn_s_setprio(1);
#pragma unroll
        for (int i = 0; i < 4; ++i)
#pragma unroll
            for (int j = 0; j < 4; ++j)
                acc[i][j] = __builtin_amdgcn_mfma_f32_16x16x32_bf16(af[i], bfr[j], acc[i][j], 0, 0, 0);
        __builtin_amdgcn_s_setprio(0);
        __builtin_amdgcn_sched_barrier(0);         // keep next glds below MFMAs (LDS WAR)
    }
    __syncthreads();                               // converge before sC reuse

    const int seg = (EPI == 1) ? (n0 >> 9) : 0;
    const float* bias = (EPI == 1) ? (seg == 0 ? bias0 : (seg == 1 ? bias1 : bias2)) : bias0;
    u16* dst = (EPI == 1) ? (seg == 0 ? out0 : (seg == 1 ? out1 : out2)) : out0;
    const int ldo = (EPI == 1) ? 512 : N;
    const int ncol0 = (EPI == 1) ? (n0 & 511) : n0;

#pragma unroll
    for (int pass = 0; pass < 2; ++pass) {
        if ((w >> 1) == pass) {
#pragma unroll
            for (int j = 0; j < 4; ++j) {
                const int col = wn + j * 16 + lr;
                const float bv = bias[ncol0 + col];
#pragma unroll
                for (int i = 0; i < 4; ++i)
#pragma unroll
                    for (int r = 0; r < 4; ++r) {
                        const int row = i * 16 + (lg << 2) + r;
                        sC[row * PADC + col] = f2b(acc[i][j][r] + bv);
                    }
            }
        }
        __syncthreads();
        const int rbase = m0 + (pass << 6);
#pragma unroll
        for (int t = 0; t < 4; ++t) {
            const int idx = t * 256 + tid;
            const int row = idx >> 4;
            const int c8 = (idx & 15) << 3;
            s16x8 v8 = *(const s16x8*)(sC + row * PADC + c8);
            size_t gaddr = (size_t)(rbase + row) * ldo + ncol0 + c8;
            s16x8 o = v8;
            if constexpr (EPI == 1) {
                if (seg < 2) {
#pragma unroll
                    for (int e = 0; e < 8; ++e) {
                        float v = b2f((u16)v8[e]);
                        v = (v > 0.f) ? v + 1.f : __expf(v);   // elu+1
                        o[e] = (short)f2b(v);
                    }
                }
            } else if constexpr (EPI == 3) {
#pragma unroll
                for (int e = 0; e < 8; ++e)
                    o[e] = (short)f2b(fmaxf(b2f((u16)v8[e]), 0.f));
            }
            *(s16x8*)(dst + gaddr) = o;
        }
        __syncthreads();
    }
}

// ---------------- row-tile GEMM + residual + LayerNorm fused --------------------------
template<int K>
__global__ __launch_bounds__(512, 4)
void k_gemm_ln(const u16* __restrict__ A, const u16* __restrict__ Bt,
               const float* __restrict__ bias, const u16* __restrict__ resid,
               const float* __restrict__ g, const float* __restrict__ be,
               u16* __restrict__ xb) {
    __shared__ __align__(16) u16 smem[36864];      // 72 KB; sC[64][PADB] unions in
    u16* sC = smem;

    const int nwg = gridDim.x;
    const int cpx = nwg >> 3;
    const int wg = (blockIdx.x & 7) * cpx + (blockIdx.x >> 3);
    const int m0 = wg << 6;                        // 64 rows per block, N = 512 full
    const int tid = threadIdx.x;
    const int w = tid >> 6, l = tid & 63;
    const int wn = w << 6;
    const int lr = l & 15, lg = l >> 4;

    const int srow = tid >> 2;                     // 0..127
    const int swz = (((tid & 3) ^ ((srow >> 1) & 3)) & 3) << 3;
    const u16* ApA = A + (size_t)(m0 + (srow & 63)) * K + ((((tid & 3) ^ (((srow & 63) >> 1) & 3)) & 3) << 3);
    const u16* BpB = Bt + (size_t)srow * K + swz;

    auto stage = [&](int d, int tt) {
        const size_t ko = (size_t)tt << 5;
        if (tid < 256) glds16(ApA + ko, smem + d * 2048 + tid * 8);
#pragma unroll
        for (int c = 0; c < 4; ++c)
            glds16(BpB + ko + (size_t)(c * 128) * K,
                   smem + 4096 + d * 16384 + c * 4096 + tid * 8);
    };

    const int axk = ((lg ^ ((lr >> 1) & 3)) & 3) << 3;

    f32x4 acc[4][4] = {};
    const int ntile = K >> 5;

    stage(0, 0);
    __syncthreads();

    for (int t = 0; t < ntile; ++t) {
        const int d = t & 1;
        if (t + 1 < ntile) stage(d ^ 1, t + 1);
        const u16* sA = smem + d * 2048;
        const u16* sB = smem + 4096 + d * 16384 + wn * 32;
        s16x8 af[4], bfr[4];
#pragma unroll
        for (int i = 0; i < 4; ++i) af[i] = *(const s16x8*)(sA + (i * 16 + lr) * 32 + axk);
#pragma unroll
        for (int j = 0; j < 4; ++j) bfr[j] = *(const s16x8*)(sB + (j * 16 + lr) * 32 + axk);
        __builtin_amdgcn_s_setprio(1);
#pragma unroll
        for (int i = 0; i < 4; ++i)
#pragma unroll
            for (int j = 0; j < 4; ++j)
                acc[i][j] = __builtin_amdgcn_mfma_f32_16x16x32_bf16(af[i], bfr[j], acc[i][j], 0, 0, 0);
        __builtin_amdgcn_s_setprio(0);
        __syncthreads();
    }

#pragma unroll
    for (int j = 0; j < 4; ++j) {
        const int col = wn + j * 16 + lr;
        const float bv = bias[col];
#pragma unroll
        for (int i = 0; i < 4; ++i)
#pragma unroll
            for (int r = 0; r < 4; ++r) {
                const int row = i * 16 + (lg << 2) + r;     // 0..63
                sC[row * PADB + col] = f2b(acc[i][j][r] + bv);
            }
    }
    __syncthreads();

#pragma unroll
    for (int it = 0; it < 8; ++it) {
        const int row = it * 8 + w;                 // 0..63
        s16x8 cv = *(const s16x8*)(sC + row * PADB + l * 8);
        s16x8 rv = *(const s16x8*)(resid + (size_t)(m0 + row) * DM_ + l * 8);
        float x[8];
#pragma unroll
        for (int e = 0; e < 8; ++e) x[e] = b2f((u16)cv[e]) + b2f((u16)rv[e]);
        float sum = 0.f;
#pragma unroll
        for (int e = 0; e < 8; ++e) sum += x[e];
#pragma unroll
        for (int off = 32; off > 0; off >>= 1) sum += __shfl_xor(sum, off);
        float mu = sum * (1.f / DM_);
        float sq = 0.f;
#pragma unroll
        for (int e = 0; e < 8; ++e) { float d = x[e] - mu; sq += d * d; }
#pragma unroll
        for (int off = 32; off > 0; off >>= 1) sq += __shfl_xor(sq, off);
        float rs = rsqrtf(sq * (1.f / DM_) + 1e-5f);
        const int c = l * 8;
        const f32x4* gp = (const f32x4*)(g + c);
        const f32x4* bp = (const f32x4*)(be + c);
        f32x4 g0 = gp[0], g1 = gp[1], e0 = bp[0], e1 = bp[1];
        s16x8 pk;
#pragma unroll
        for (int e = 0; e < 4; ++e) pk[e] = (short)f2b((x[e] - mu) * rs * g0[e] + e0[e]);
#pragma unroll
        for (int e = 0; e < 4; ++e) pk[4 + e] = (short)f2b((x[4 + e] - mu) * rs * g1[e] + e1[e]);
        *(s16x8*)(xb + (size_t)(m0 + row) * DM_ + c) = pk;
    }
}

// ---------------- kv einsum partials ---------------------------------------------------
__global__ __launch_bounds__(256)
void k_kv(const u16* __restrict__ kb_, const u16* __restrict__ vb_,
          float* __restrict__ kvp, float* __restrict__ ksump) {
    __shared__ float sk[64 * 68], sv[64 * 68];
    int bh = blockIdx.x, b = bh >> 3, h = bh & 7;
    int ch = blockIdx.y;
    int tid = threadIdx.x;
    int d0 = (tid & 15) << 2, m0 = (tid >> 4) << 2;
    float acc[4][4] = {};
    float ks[4] = {0.f, 0.f, 0.f, 0.f};
    size_t gbase = ((size_t)b * SEQ_ + (size_t)ch * (SEQ_ / NCH)) * DM_ + h * 64;

    for (int st = 0; st < SEQ_ / NCH; st += 64) {
#pragma unroll
        for (int i = 0; i < 2; ++i) {
            int li = tid + (i << 8);
            int r = li >> 3, c8 = (li & 7) << 3;
            s16x8 kv_ = *(const s16x8*)(kb_ + gbase + (size_t)(st + r) * DM_ + c8);
            s16x8 vv_ = *(const s16x8*)(vb_ + gbase + (size_t)(st + r) * DM_ + c8);
#pragma unroll
            for (int e = 0; e < 8; ++e) {
                sk[r * 68 + c8 + e] = b2f((u16)kv_[e]);
                sv[r * 68 + c8 + e] = b2f((u16)vv_[e]);
            }
        }
        __syncthreads();
        for (int s = 0; s < 64; ++s) {
            f32x4 kd = *(const f32x4*)(sk + s * 68 + d0);
            f32x4 vm = *(const f32x4*)(sv + s * 68 + m0);
#pragma unroll
            for (int i = 0; i < 4; ++i)
#pragma unroll
                for (int j = 0; j < 4; ++j) acc[i][j] += kd[i] * vm[j];
            if ((tid >> 4) == 0) { ks[0] += kd[0]; ks[1] += kd[1]; ks[2] += kd[2]; ks[3] += kd[3]; }
        }
        __syncthreads();
    }
    float* kvo = kvp + ((size_t)ch * 64 + bh) * 4096;
#pragma unroll
    for (int i = 0; i < 4; ++i)
#pragma unroll
        for (int j = 0; j < 4; ++j) kvo[(d0 + i) * 64 + m0 + j] = acc[i][j];
    if ((tid >> 4) == 0) {
        float* kso = ksump + ((size_t)ch * 64 + bh) * 64;
#pragma unroll
        for (int e = 0; e < 4; ++e) kso[d0 + e] = ks[e];
    }
}

// ---------------- reduce partials once: kvt bf16 [bh][m][d swizzled] + ksum f32 -------
__global__ __launch_bounds__(256)
void k_red(const float* __restrict__ kvp, const float* __restrict__ ksump,
           u16* __restrict__ kvt, float* __restrict__ ksum) {
    int bh = blockIdx.x, q = blockIdx.y;           // q in 0..3
    int tid = threadIdx.x;
#pragma unroll
    for (int p = 0; p < 4; ++p) {
        int i = (q * 4 + p) * 256 + tid;           // i = d*64 + m
        float v = 0.f;
#pragma unroll
        for (int c = 0; c < NCH; ++c) v += kvp[((size_t)c * 64 + bh) * 4096 + i];
        int d = i >> 6, m = i & 63;
        int slot = ((d >> 3) ^ (m & 7)) & 7;
        kvt[(size_t)bh * 4096 + m * 64 + slot * 8 + (d & 7)] = f2b(v);
    }
    if (q == 0 && tid < 64) {
        float v = 0.f;
#pragma unroll
        for (int c = 0; c < NCH; ++c) v += ksump[((size_t)c * 64 + bh) * 64 + tid];
        ksum[bh * 64 + tid] = v;
    }
}

// ---------------- attention apply via MFMA: a = (q . kv) * z --------------------------
__global__ __launch_bounds__(256)
void k_attn(const u16* __restrict__ qb_, const u16* __restrict__ kvt,
            const float* __restrict__ ksum, u16* __restrict__ ab_) {
    __shared__ __align__(16) u16 qs[256 * 64];     // 32KB (reused as output bounce)
    __shared__ __align__(16) u16 skv[64 * 64];     // 8KB
    __shared__ float sden[256];
    __shared__ float sks[64];
    const int tid = threadIdx.x;
    const int bh = blockIdx.y, b = bh >> 3, h = bh & 7;
    const int s0 = blockIdx.x << 8;                // 256 rows
    const int w = tid >> 6, l = tid & 63;
    const int lr = l & 15, lg = l >> 4;

    {
        const int srw = tid >> 3, ch = tid & 7;
        const int scol = ((ch ^ (srw & 7)) & 7) << 3;
        const u16* qsrc = qb_ + ((size_t)b * SEQ_ + s0 + srw) * DM_ + h * 64 + scol;
#pragma unroll
        for (int p = 0; p < 8; ++p)
            glds16(qsrc + (size_t)(p * 32) * DM_, qs + p * 2048 + tid * 8);
#pragma unroll
        for (int p = 0; p < 2; ++p)
            glds16(kvt + (size_t)bh * 4096 + p * 2048 + tid * 8, skv + p * 2048 + tid * 8);
    }
    if (tid < 64) sks[tid] = ksum[bh * 64 + tid];
    __syncthreads();

    {
        const int row = (w << 6) + l;
        float den = 0.f;
#pragma unroll
        for (int c = 0; c < 8; ++c) {
            s16x8 qv = *(const s16x8*)(qs + row * 64 + (((c ^ (row & 7)) & 7) << 3));
#pragma unroll
            for (int e = 0; e < 8; ++e) den += b2f((u16)qv[e]) * sks[c * 8 + e];
        }
        sden[row] = 1.f / (den + 1e-6f);
    }
    __syncthreads();

    f32x4 acc[4][4] = {};
#pragma unroll
    for (int kh = 0; kh < 2; ++kh) {
        const int c = kh * 4 + lg;
        s16x8 bfr[4];
#pragma unroll
        for (int j = 0; j < 4; ++j) {
            const int mm = j * 16 + lr;
            bfr[j] = *(const s16x8*)(skv + mm * 64 + (((c ^ (mm & 7)) & 7) << 3));
        }
#pragma unroll
        for (int i = 0; i < 4; ++i) {
            const int rr = (w << 6) + i * 16 + lr;
            s16x8 af = *(const s16x8*)(qs + rr * 64 + (((c ^ (rr & 7)) & 7) << 3));
#pragma unroll
            for (int j = 0; j < 4; ++j)
                acc[i][j] = __builtin_amdgcn_mfma_f32_16x16x32_bf16(af, bfr[j], acc[i][j], 0, 0, 0);
        }
    }
    __syncthreads();                               // all qs reads done; reuse as bounce

#pragma unroll
    for (int i = 0; i < 4; ++i) {
#pragma unroll
        for (int r = 0; r < 4; ++r) {
            const int row = (w << 6) + i * 16 + (lg << 2) + r;
            const float z = sden[row];
#pragma unroll
            for (int j = 0; j < 4; ++j)
                qs[row * 64 + j * 16 + lr] = f2b(acc[i][j][r] * z);
        }
    }
    __syncthreads();
    {
        const int srw = tid >> 3, ch = tid & 7;
        u16* odst = ab_ + ((size_t)b * SEQ_ + s0 + srw) * DM_ + h * 64 + ch * 8;
#pragma unroll
        for (int p = 0; p < 8; ++p)
            *(s16x8*)(odst + (size_t)(p * 32) * DM_) = *(const s16x8*)(qs + p * 2048 + tid * 8);
    }
}

// ---------------- final LN + Wout dot (bf16 in) ----------------------------------------
__global__ __launch_bounds__(256)
void k_final(const u16* __restrict__ in, const float* __restrict__ gf,
             const float* __restrict__ bf_, const float* __restrict__ wout,
             const float* __restrict__ bout, float* __restrict__ out) {
    int row = blockIdx.x * 4 + (threadIdx.x >> 6);
    int l = threadIdx.x & 63;
    s16x8 raw = *(const s16x8*)(in + (size_t)row * DM_ + l * 8);
    float x[8];
#pragma unroll
    for (int e = 0; e < 8; ++e) x[e] = b2f((u16)raw[e]);
    float sum = 0.f;
#pragma unroll
    for (int e = 0; e < 8; ++e) sum += x[e];
#pragma unroll
    for (int off = 32; off > 0; off >>= 1) sum += __shfl_xor(sum, off);
    float mu = sum * (1.f / DM_);
    float sq = 0.f;
#pragma unroll
    for (int e = 0; e < 8; ++e) { float d = x[e] - mu; sq += d * d; }
#pragma unroll
    for (int off = 32; off > 0; off >>= 1) sq += __shfl_xor(sq, off);
    float rs = rsqrtf(sq * (1.f / DM_) + 1e-5f);
    int c = l * 8;
    float p = 0.f;
#pragma unroll
    for (int e = 0; e < 8; ++e)
        p += ((x[e] - mu) * rs * gf[c + e] + bf_[c + e]) * wout[c + e];
#pragma unroll
    for (int off = 32; off > 0; off >>= 1) p += __shfl_xor(p, off);
    if (l == 0) out[row] = p + bout[0];
}

// =======================================================================================
extern "C" void kernel_launch(void* const* d_in, const int* in_sizes, int n_in,
                              void* d_out, int out_size, void* d_ws, size_t ws_size,
                              hipStream_t stream) {
    const float* emb   = (const float*)d_in[0];
    const float* W0    = (const float*)d_in[1];
    const float* b0    = (const float*)d_in[2];
    const float* Wq    = (const float*)d_in[3];
    const float* bq    = (const float*)d_in[4];
    const float* Wk    = (const float*)d_in[5];
    const float* bk    = (const float*)d_in[6];
    const float* Wv    = (const float*)d_in[7];
    const float* bv    = (const float*)d_in[8];
    const float* Wo    = (const float*)d_in[9];
    const float* bo    = (const float*)d_in[10];
    const float* ln1s  = (const float*)d_in[11];
    const float* ln1b  = (const float*)d_in[12];
    const float* W1    = (const float*)d_in[13];
    const float* b1    = (const float*)d_in[14];
    const float* W2    = (const float*)d_in[15];
    const float* b2    = (const float*)d_in[16];
    const float* ln2s  = (const float*)d_in[17];
    const float* ln2b  = (const float*)d_in[18];
    const float* lnfs  = (const float*)d_in[19];
    const float* lnfb  = (const float*)d_in[20];
    const float* Wout  = (const float*)d_in[21];
    const float* bout  = (const float*)d_in[22];
    float* out = (float*)d_out;

    char* ws = (char*)d_ws;
    size_t off = 0;
    auto alloc = [&](size_t bytes) -> void* {
        void* p = ws + off;
        off += (bytes + 255) & ~(size_t)255;
        return p;
    };
    u16* xb   = (u16*)alloc((size_t)BS_ * DM_ * 2);    // 32MB  x (bf16 stream)
    u16* qb   = (u16*)alloc((size_t)BS_ * DM_ * 2);    // 32MB
    u16* kb   = (u16*)alloc((size_t)BS_ * DM_ * 2);    // 32MB
    u16* vb   = (u16*)alloc((size_t)BS_ * DM_ * 2);    // 32MB
    float* kvp   = (float*)alloc((size_t)NCH * 64 * 4096 * 4);   // 8MB
    float* ksump = (float*)alloc((size_t)NCH * 64 * 64 * 4);
    u16* kvt  = (u16*)alloc((size_t)64 * 4096 * 2);    // 512KB
    float* ksum = (float*)alloc((size_t)64 * 64 * 4);
    u16* wp   = (u16*)alloc((size_t)4521984 * 2);      // weight pool ~9MB

    u16* ab   = vb;    // attn output (written after vb consumed)
    u16* h1b  = kb;    // 64MB FF hidden = kb+vb regions
    u16* embp = kb;    // 38MB emb bf16 padded = kb+vb regions (dead before QKV)

    u16* W0t  = wp;                          // [512][608]
    u16* Wqkv = wp + 311296;                 // per layer [1536][512]
    u16* Wot  = Wqkv + 2 * 786432;           // per layer [512][512]
    u16* W1t  = Wot + 2 * 262144;            // per layer [1024][512]
    u16* W2t  = W1t + 2 * 524288;            // per layer [512][1024]

    k_tr_all<<<4400, dim3(32, 8), 0, stream>>>(W0, Wq, Wk, Wv, Wo, W1, W2,
                                               W0t, Wqkv, Wot, W1t, W2t);
    k_emb<<<2560, 256, 0, stream>>>(emb, embp);

    // x = emb @ W0 + b0
    k_gemm<0><<<1024, 256, 0, stream>>>(embp, W0t, b0, nullptr, nullptr,
                                        xb, nullptr, nullptr, BS_, DM_, FINP_, 4);

    for (int l = 0; l < 2; ++l) {
        // fused QKV: N=1536, feat(elu+1) on q,k
        k_gemm<1><<<3072, 256, 0, stream>>>(xb, Wqkv + (size_t)l * 786432,
                                            bq + l * 512, bk + l * 512, bv + l * 512,
                                            qb, kb, vb, BS_, 1536, 512, 12);
        k_kv<<<dim3(64, NCH), 256, 0, stream>>>(kb, vb, kvp, ksump);
        k_red<<<dim3(64, 4), 256, 0, stream>>>(kvp, ksump, kvt, ksum);
        k_attn<<<dim3(16, 64), 256, 0, stream>>>(qb, kvt, ksum, ab);
        // x = LN1(x + a@Wo + bo)   (fused: GEMM + resid + LN)
        k_gemm_ln<512><<<512, 512, 0, stream>>>(ab, Wot + (size_t)l * 262144,
                                                bo + l * 512, xb,
                                                ln1s + l * 512, ln1b + l * 512, xb);
        // h = relu(x@W1+b1)
        k_gemm<3><<<2048, 256, 0, stream>>>(xb, W1t + (size_t)l * 524288,
                                            b1 + l * 1024, nullptr, nullptr,
                                            h1b, nullptr, nullptr, BS_, 1024, 512, 8);
        // x = LN2(x + h@W2 + b2)   (fused)
        k_gemm_ln<1024><<<512, 512, 0, stream>>>(h1b, W2t + (size_t)l * 524288,
                                                 b2 + l * 512, xb,
                                                 ln2s + l * 512, ln2b + l * 512, xb);
    }
    k_final<<<8192, 256, 0, stream>>>(xb, lnfs, lnfb, Wout, bout, out);
}

// Round 21
// 591.805 us; speedup vs baseline: 1.1555x; 1.1460x over previous
//
#include <hip/hip_runtime.h>
#include <hip/hip_bf16.h>
#include <math.h>

typedef unsigned short u16;
typedef short s16x8 __attribute__((ext_vector_type(8)));
typedef float f32x4 __attribute__((ext_vector_type(4)));

#define BS_   32768      // B*S
#define SEQ_  4096
#define DM_   512
#define FF_   1024
#define FIN_  586
#define FINP_ 608        // emb K padded to 19*32
#define PADC  136        // epilogue LDS stride (u16), 128-wide tiles
#define PADB  520        // epilogue LDS stride (u16), 512-wide rows
#define NCH   8          // kv S-chunks

__device__ __forceinline__ u16 f2b(float f) {
    __hip_bfloat16 h = __float2bfloat16(f);      // RNE, hw v_cvt on gfx950
    return *reinterpret_cast<u16*>(&h);
}
__device__ __forceinline__ float b2f(u16 h) {
    union { unsigned u; float f; } a; a.u = ((unsigned)h) << 16;
    return a.f;
}

typedef __attribute__((address_space(1))) const unsigned gu32;
typedef __attribute__((address_space(3))) unsigned lu32;
__device__ __forceinline__ void glds16(const void* g, void* l) {
    __builtin_amdgcn_global_load_lds((gu32*)g, (lu32*)l, 16, 0, 0);
}

// ---------------- batched weight transpose + bf16 convert (one launch) ----------------
__device__ __forceinline__ void tr_tile(const float* __restrict__ W, u16* __restrict__ Wt,
                                        int K, int N, int Kpad, int tidx, int ktiles,
                                        float (*t)[33]) {
    int kb = (tidx % ktiles) << 5, nb = (tidx / ktiles) << 5;
    int tx = threadIdx.x, ty = threadIdx.y;          // 32 x 8
#pragma unroll
    for (int j = 0; j < 32; j += 8) {
        int k = kb + ty + j;
        t[ty + j][tx] = (k < K) ? W[(size_t)k * N + nb + tx] : 0.f;
    }
    __syncthreads();
#pragma unroll
    for (int j = 0; j < 32; j += 8) {
        Wt[(size_t)(nb + ty + j) * Kpad + kb + tx] = f2b(t[tx][ty + j]);
    }
}

__global__ void k_tr_all(const float* __restrict__ W0, const float* __restrict__ Wq,
                         const float* __restrict__ Wk, const float* __restrict__ Wv,
                         const float* __restrict__ Wo, const float* __restrict__ W1,
                         const float* __restrict__ W2,
                         u16* __restrict__ W0t, u16* __restrict__ Wqkv,
                         u16* __restrict__ Wot, u16* __restrict__ W1t,
                         u16* __restrict__ W2t) {
    __shared__ float t[32][33];
    int b = blockIdx.x;
    if (b < 304) { tr_tile(W0, W0t, FIN_, DM_, FINP_, b, 19, t); return; }   // 19x16 tiles
    b -= 304;
    int l = b >> 11;              // 2048 tiles per layer
    int r = b & 2047;
    if (r < 768) {                // q,k,v : 256 tiles each
        int sel = r >> 8, ti = r & 255;
        const float* src = sel == 0 ? Wq : (sel == 1 ? Wk : Wv);
        tr_tile(src + (size_t)l * 262144, Wqkv + (size_t)l * 786432 + (size_t)sel * 262144,
                512, 512, 512, ti, 16, t);
    } else if (r < 1024) {
        tr_tile(Wo + (size_t)l * 262144, Wot + (size_t)l * 262144, 512, 512, 512, r - 768, 16, t);
    } else if (r < 1536) {
        tr_tile(W1 + (size_t)l * 524288, W1t + (size_t)l * 524288, 512, 1024, 512, r - 1024, 16, t);
    } else {
        tr_tile(W2 + (size_t)l * 524288, W2t + (size_t)l * 524288, 1024, 512, 1024, r - 1536, 32, t);
    }
}

// ---------------- embeddings -> bf16 padded [BS][608] ---------------------------------
__global__ __launch_bounds__(256)
void k_emb(const float* __restrict__ E, u16* __restrict__ Ep) {
    const int total8 = BS_ * (FINP_ / 8);
    for (int i = blockIdx.x * 256 + threadIdx.x; i < total8; i += gridDim.x * 256) {
        int rr = i / (FINP_ / 8), c = (i % (FINP_ / 8)) * 8;
        const float* rp = E + (size_t)rr * FIN_ + c;
        s16x8 o;
#pragma unroll
        for (int e = 0; e < 8; ++e) {
            float v = (c + e < FIN_) ? rp[e] : 0.f;
            o[e] = (short)f2b(v);
        }
        *(s16x8*)(Ep + (size_t)rr * FINP_ + c) = o;
    }
}

// ---------------- MFMA GEMM: 128x128, BK=32, dbuf, 32KB LDS, 4 blocks/CU --------------
// 8-slot swizzle: stage source chunk = (tid&3)^((srow>>1)&3); read = lg^((lr>>1)&3).
// EPI: 0 = bias only, 1 = QKV split (feat on q,k), 3 = relu
template<int EPI>
__global__ __launch_bounds__(256, 4)
void k_gemm(const u16* __restrict__ A, const u16* __restrict__ Bt,
            const float* __restrict__ bias0, const float* __restrict__ bias1,
            const float* __restrict__ bias2,
            u16* __restrict__ out0, u16* __restrict__ out1, u16* __restrict__ out2,
            int M, int N, int K, int NT) {
    __shared__ __align__(16) u16 smem[16384];      // 32 KB; sC epilogue unions in
    u16* sC = smem;

    const int nwg = gridDim.x;
    const int cpx = nwg >> 3;                      // nwg % 8 == 0 for all launches here
    const int wg = (blockIdx.x & 7) * cpx + (blockIdx.x >> 3);
    const int mt = wg / NT, nt = wg - mt * NT;
    const int m0 = mt << 7, n0 = nt << 7;
    const int tid = threadIdx.x;
    const int w = tid >> 6, l = tid & 63;
    const int wm = (w >> 1) << 6, wn = (w & 1) << 6;
    const int lr = l & 15, lg = l >> 4;

    const int srow = tid >> 2;                     // 0..63
    const int swz = (((tid & 3) ^ ((srow >> 1) & 3)) & 3) << 3;   // 8-slot swizzle source
    const u16* Ap = A + (size_t)(m0 + srow) * K + swz;
    const u16* Bp = Bt + (size_t)(n0 + srow) * K + swz;

    auto stage = [&](int d, int tt) {
        const size_t ko = (size_t)tt << 5;
        u16* da = smem + d * 4096 + tid * 8;
        u16* db = smem + 8192 + d * 4096 + tid * 8;
        glds16(Ap + ko, da);
        glds16(Ap + ko + (size_t)64 * K, da + 2048);
        glds16(Bp + ko, db);
        glds16(Bp + ko + (size_t)64 * K, db + 2048);
    };

    const int axk = ((lg ^ ((lr >> 1) & 3)) & 3) << 3;   // read-side swizzle

    f32x4 acc[4][4] = {};
    const int ntile = K >> 5;

    stage(0, 0);
    __syncthreads();

    for (int t = 0; t < ntile; ++t) {
        const int d = t & 1;
        if (t + 1 < ntile) stage(d ^ 1, t + 1);
        const u16* sA = smem + d * 4096;
        const u16* sB = smem + 8192 + d * 4096;
        s16x8 af[4], bfr[4];
#pragma unroll
        for (int i = 0; i < 4; ++i) af[i] = *(const s16x8*)(sA + (wm + i * 16 + lr) * 32 + axk);
#pragma unroll
        for (int j = 0; j < 4; ++j) bfr[j] = *(const s16x8*)(sB + (wn + j * 16 + lr) * 32 + axk);
        __builtin_amdgcn_s_setprio(1);
#pragma unroll
        for (int i = 0; i < 4; ++i)
#pragma unroll
            for (int j = 0; j < 4; ++j)
                acc[i][j] = __builtin_amdgcn_mfma_f32_16x16x32_bf16(af[i], bfr[j], acc[i][j], 0, 0, 0);
        __builtin_amdgcn_s_setprio(0);
        __syncthreads();
    }

    const int seg = (EPI == 1) ? (n0 >> 9) : 0;
    const float* bias = (EPI == 1) ? (seg == 0 ? bias0 : (seg == 1 ? bias1 : bias2)) : bias0;
    u16* dst = (EPI == 1) ? (seg == 0 ? out0 : (seg == 1 ? out1 : out2)) : out0;
    const int ldo = (EPI == 1) ? 512 : N;
    const int ncol0 = (EPI == 1) ? (n0 & 511) : n0;

#pragma unroll
    for (int pass = 0; pass < 2; ++pass) {
        if ((w >> 1) == pass) {
#pragma unroll
            for (int j = 0; j < 4; ++j) {
                const int col = wn + j * 16 + lr;
                const float bv = bias[ncol0 + col];
#pragma unroll
                for (int i = 0; i < 4; ++i)
#pragma unroll
                    for (int r = 0; r < 4; ++r) {
                        const int row = i * 16 + (lg << 2) + r;
                        sC[row * PADC + col] = f2b(acc[i][j][r] + bv);
                    }
            }
        }
        __syncthreads();
        const int rbase = m0 + (pass << 6);
#pragma unroll
        for (int t = 0; t < 4; ++t) {
            const int idx = t * 256 + tid;
            const int row = idx >> 4;
            const int c8 = (idx & 15) << 3;
            s16x8 v8 = *(const s16x8*)(sC + row * PADC + c8);
            size_t gaddr = (size_t)(rbase + row) * ldo + ncol0 + c8;
            s16x8 o = v8;
            if constexpr (EPI == 1) {
                if (seg < 2) {
#pragma unroll
                    for (int e = 0; e < 8; ++e) {
                        float v = b2f((u16)v8[e]);
                        v = (v > 0.f) ? v + 1.f : __expf(v);   // elu+1
                        o[e] = (short)f2b(v);
                    }
                }
            } else if constexpr (EPI == 3) {
#pragma unroll
                for (int e = 0; e < 8; ++e)
                    o[e] = (short)f2b(fmaxf(b2f((u16)v8[e]), 0.f));
            }
            *(s16x8*)(dst + gaddr) = o;
        }
        __syncthreads();
    }
}

// ---------------- row-tile GEMM + residual + LayerNorm fused --------------------------
template<int K>
__global__ __launch_bounds__(512, 4)
void k_gemm_ln(const u16* __restrict__ A, const u16* __restrict__ Bt,
               const float* __restrict__ bias, const u16* __restrict__ resid,
               const float* __restrict__ g, const float* __restrict__ be,
               u16* __restrict__ xb) {
    __shared__ __align__(16) u16 smem[36864];      // 72 KB; sC[64][PADB] unions in
    u16* sC = smem;

    const int nwg = gridDim.x;
    const int cpx = nwg >> 3;
    const int wg = (blockIdx.x & 7) * cpx + (blockIdx.x >> 3);
    const int m0 = wg << 6;                        // 64 rows per block, N = 512 full
    const int tid = threadIdx.x;
    const int w = tid >> 6, l = tid & 63;
    const int wn = w << 6;
    const int lr = l & 15, lg = l >> 4;

    const int srow = tid >> 2;                     // 0..127
    const int swz = (((tid & 3) ^ ((srow >> 1) & 3)) & 3) << 3;
    const u16* ApA = A + (size_t)(m0 + (srow & 63)) * K + ((((tid & 3) ^ (((srow & 63) >> 1) & 3)) & 3) << 3);
    const u16* BpB = Bt + (size_t)srow * K + swz;

    auto stage = [&](int d, int tt) {
        const size_t ko = (size_t)tt << 5;
        if (tid < 256) glds16(ApA + ko, smem + d * 2048 + tid * 8);
#pragma unroll
        for (int c = 0; c < 4; ++c)
            glds16(BpB + ko + (size_t)(c * 128) * K,
                   smem + 4096 + d * 16384 + c * 4096 + tid * 8);
    };

    const int axk = ((lg ^ ((lr >> 1) & 3)) & 3) << 3;

    f32x4 acc[4][4] = {};
    const int ntile = K >> 5;

    stage(0, 0);
    __syncthreads();

    for (int t = 0; t < ntile; ++t) {
        const int d = t & 1;
        if (t + 1 < ntile) stage(d ^ 1, t + 1);
        const u16* sA = smem + d * 2048;
        const u16* sB = smem + 4096 + d * 16384 + wn * 32;
        s16x8 af[4], bfr[4];
#pragma unroll
        for (int i = 0; i < 4; ++i) af[i] = *(const s16x8*)(sA + (i * 16 + lr) * 32 + axk);
#pragma unroll
        for (int j = 0; j < 4; ++j) bfr[j] = *(const s16x8*)(sB + (j * 16 + lr) * 32 + axk);
        __builtin_amdgcn_s_setprio(1);
#pragma unroll
        for (int i = 0; i < 4; ++i)
#pragma unroll
            for (int j = 0; j < 4; ++j)
                acc[i][j] = __builtin_amdgcn_mfma_f32_16x16x32_bf16(af[i], bfr[j], acc[i][j], 0, 0, 0);
        __builtin_amdgcn_s_setprio(0);
        __syncthreads();
    }

#pragma unroll
    for (int j = 0; j < 4; ++j) {
        const int col = wn + j * 16 + lr;
        const float bv = bias[col];
#pragma unroll
        for (int i = 0; i < 4; ++i)
#pragma unroll
            for (int r = 0; r < 4; ++r) {
                const int row = i * 16 + (lg << 2) + r;     // 0..63
                sC[row * PADB + col] = f2b(acc[i][j][r] + bv);
            }
    }
    __syncthreads();

#pragma unroll
    for (int it = 0; it < 8; ++it) {
        const int row = it * 8 + w;                 // 0..63
        s16x8 cv = *(const s16x8*)(sC + row * PADB + l * 8);
        s16x8 rv = *(const s16x8*)(resid + (size_t)(m0 + row) * DM_ + l * 8);
        float x[8];
#pragma unroll
        for (int e = 0; e < 8; ++e) x[e] = b2f((u16)cv[e]) + b2f((u16)rv[e]);
        float sum = 0.f;
#pragma unroll
        for (int e = 0; e < 8; ++e) sum += x[e];
#pragma unroll
        for (int off = 32; off > 0; off >>= 1) sum += __shfl_xor(sum, off);
        float mu = sum * (1.f / DM_);
        float sq = 0.f;
#pragma unroll
        for (int e = 0; e < 8; ++e) { float d = x[e] - mu; sq += d * d; }
#pragma unroll
        for (int off = 32; off > 0; off >>= 1) sq += __shfl_xor(sq, off);
        float rs = rsqrtf(sq * (1.f / DM_) + 1e-5f);
        const int c = l * 8;
        const f32x4* gp = (const f32x4*)(g + c);
        const f32x4* bp = (const f32x4*)(be + c);
        f32x4 g0 = gp[0], g1 = gp[1], e0 = bp[0], e1 = bp[1];
        s16x8 pk;
#pragma unroll
        for (int e = 0; e < 4; ++e) pk[e] = (short)f2b((x[e] - mu) * rs * g0[e] + e0[e]);
#pragma unroll
        for (int e = 0; e < 4; ++e) pk[4 + e] = (short)f2b((x[4 + e] - mu) * rs * g1[e] + e1[e]);
        *(s16x8*)(xb + (size_t)(m0 + row) * DM_ + c) = pk;
    }
}

// ---------------- kv einsum partials ---------------------------------------------------
__global__ __launch_bounds__(256)
void k_kv(const u16* __restrict__ kb_, const u16* __restrict__ vb_,
          float* __restrict__ kvp, float* __restrict__ ksump) {
    __shared__ float sk[64 * 68], sv[64 * 68];
    int bh = blockIdx.x, b = bh >> 3, h = bh & 7;
    int ch = blockIdx.y;
    int tid = threadIdx.x;
    int d0 = (tid & 15) << 2, m0 = (tid >> 4) << 2;
    float acc[4][4] = {};
    float ks[4] = {0.f, 0.f, 0.f, 0.f};
    size_t gbase = ((size_t)b * SEQ_ + (size_t)ch * (SEQ_ / NCH)) * DM_ + h * 64;

    for (int st = 0; st < SEQ_ / NCH; st += 64) {
#pragma unroll
        for (int i = 0; i < 2; ++i) {
            int li = tid + (i << 8);
            int r = li >> 3, c8 = (li & 7) << 3;
            s16x8 kv_ = *(const s16x8*)(kb_ + gbase + (size_t)(st + r) * DM_ + c8);
            s16x8 vv_ = *(const s16x8*)(vb_ + gbase + (size_t)(st + r) * DM_ + c8);
#pragma unroll
            for (int e = 0; e < 8; ++e) {
                sk[r * 68 + c8 + e] = b2f((u16)kv_[e]);
                sv[r * 68 + c8 + e] = b2f((u16)vv_[e]);
            }
        }
        __syncthreads();
        for (int s = 0; s < 64; ++s) {
            f32x4 kd = *(const f32x4*)(sk + s * 68 + d0);
            f32x4 vm = *(const f32x4*)(sv + s * 68 + m0);
#pragma unroll
            for (int i = 0; i < 4; ++i)
#pragma unroll
                for (int j = 0; j < 4; ++j) acc[i][j] += kd[i] * vm[j];
            if ((tid >> 4) == 0) { ks[0] += kd[0]; ks[1] += kd[1]; ks[2] += kd[2]; ks[3] += kd[3]; }
        }
        __syncthreads();
    }
    float* kvo = kvp + ((size_t)ch * 64 + bh) * 4096;
#pragma unroll
    for (int i = 0; i < 4; ++i)
#pragma unroll
        for (int j = 0; j < 4; ++j) kvo[(d0 + i) * 64 + m0 + j] = acc[i][j];
    if ((tid >> 4) == 0) {
        float* kso = ksump + ((size_t)ch * 64 + bh) * 64;
#pragma unroll
        for (int e = 0; e < 4; ++e) kso[d0 + e] = ks[e];
    }
}

// ---------------- reduce partials once: kvt bf16 [bh][m][d swizzled] + ksum f32 -------
__global__ __launch_bounds__(256)
void k_red(const float* __restrict__ kvp, const float* __restrict__ ksump,
           u16* __restrict__ kvt, float* __restrict__ ksum) {
    int bh = blockIdx.x, q = blockIdx.y;           // q in 0..3
    int tid = threadIdx.x;
#pragma unroll
    for (int p = 0; p < 4; ++p) {
        int i = (q * 4 + p) * 256 + tid;           // i = d*64 + m
        float v = 0.f;
#pragma unroll
        for (int c = 0; c < NCH; ++c) v += kvp[((size_t)c * 64 + bh) * 4096 + i];
        int d = i >> 6, m = i & 63;
        int slot = ((d >> 3) ^ (m & 7)) & 7;
        kvt[(size_t)bh * 4096 + m * 64 + slot * 8 + (d & 7)] = f2b(v);
    }
    if (q == 0 && tid < 64) {
        float v = 0.f;
#pragma unroll
        for (int c = 0; c < NCH; ++c) v += ksump[((size_t)c * 64 + bh) * 64 + tid];
        ksum[bh * 64 + tid] = v;
    }
}

// ---------------- attention apply via MFMA: a = (q . kv) * z --------------------------
__global__ __launch_bounds__(256)
void k_attn(const u16* __restrict__ qb_, const u16* __restrict__ kvt,
            const float* __restrict__ ksum, u16* __restrict__ ab_) {
    __shared__ __align__(16) u16 qs[256 * 64];     // 32KB (reused as output bounce)
    __shared__ __align__(16) u16 skv[64 * 64];     // 8KB
    __shared__ float sden[256];
    __shared__ float sks[64];
    const int tid = threadIdx.x;
    const int bh = blockIdx.y, b = bh >> 3, h = bh & 7;
    const int s0 = blockIdx.x << 8;                // 256 rows
    const int w = tid >> 6, l = tid & 63;
    const int lr = l & 15, lg = l >> 4;

    {
        const int srw = tid >> 3, ch = tid & 7;
        const int scol = ((ch ^ (srw & 7)) & 7) << 3;
        const u16* qsrc = qb_ + ((size_t)b * SEQ_ + s0 + srw) * DM_ + h * 64 + scol;
#pragma unroll
        for (int p = 0; p < 8; ++p)
            glds16(qsrc + (size_t)(p * 32) * DM_, qs + p * 2048 + tid * 8);
#pragma unroll
        for (int p = 0; p < 2; ++p)
            glds16(kvt + (size_t)bh * 4096 + p * 2048 + tid * 8, skv + p * 2048 + tid * 8);
    }
    if (tid < 64) sks[tid] = ksum[bh * 64 + tid];
    __syncthreads();

    {
        const int row = (w << 6) + l;
        float den = 0.f;
#pragma unroll
        for (int c = 0; c < 8; ++c) {
            s16x8 qv = *(const s16x8*)(qs + row * 64 + (((c ^ (row & 7)) & 7) << 3));
#pragma unroll
            for (int e = 0; e < 8; ++e) den += b2f((u16)qv[e]) * sks[c * 8 + e];
        }
        sden[row] = 1.f / (den + 1e-6f);
    }
    __syncthreads();

    f32x4 acc[4][4] = {};
#pragma unroll
    for (int kh = 0; kh < 2; ++kh) {
        const int c = kh * 4 + lg;
        s16x8 bfr[4];
#pragma unroll
        for (int j = 0; j < 4; ++j) {
            const int mm = j * 16 + lr;
            bfr[j] = *(const s16x8*)(skv + mm * 64 + (((c ^ (mm & 7)) & 7) << 3));
        }
#pragma unroll
        for (int i = 0; i < 4; ++i) {
            const int rr = (w << 6) + i * 16 + lr;
            s16x8 af = *(const s16x8*)(qs + rr * 64 + (((c ^ (rr & 7)) & 7) << 3));
#pragma unroll
            for (int j = 0; j < 4; ++j)
                acc[i][j] = __builtin_amdgcn_mfma_f32_16x16x32_bf16(af, bfr[j], acc[i][j], 0, 0, 0);
        }
    }
    __syncthreads();                               // all qs reads done; reuse as bounce

#pragma unroll
    for (int i = 0; i < 4; ++i) {
#pragma unroll
        for (int r = 0; r < 4; ++r) {
            const int row = (w << 6) + i * 16 + (lg << 2) + r;
            const float z = sden[row];
#pragma unroll
            for (int j = 0; j < 4; ++j)
                qs[row * 64 + j * 16 + lr] = f2b(acc[i][j][r] * z);
        }
    }
    __syncthreads();
    {
        const int srw = tid >> 3, ch = tid & 7;
        u16* odst = ab_ + ((size_t)b * SEQ_ + s0 + srw) * DM_ + h * 64 + ch * 8;
#pragma unroll
        for (int p = 0; p < 8; ++p)
            *(s16x8*)(odst + (size_t)(p * 32) * DM_) = *(const s16x8*)(qs + p * 2048 + tid * 8);
    }
}

// ---------------- final LN + Wout dot (bf16 in) ----------------------------------------
__global__ __launch_bounds__(256)
void k_final(const u16* __restrict__ in, const float* __restrict__ gf,
             const float* __restrict__ bf_, const float* __restrict__ wout,
             const float* __restrict__ bout, float* __restrict__ out) {
    int row = blockIdx.x * 4 + (threadIdx.x >> 6);
    int l = threadIdx.x & 63;
    s16x8 raw = *(const s16x8*)(in + (size_t)row * DM_ + l * 8);
    float x[8];
#pragma unroll
    for (int e = 0; e < 8; ++e) x[e] = b2f((u16)raw[e]);
    float sum = 0.f;
#pragma unroll
    for (int e = 0; e < 8; ++e) sum += x[e];
#pragma unroll
    for (int off = 32; off > 0; off >>= 1) sum += __shfl_xor(sum, off);
    float mu = sum * (1.f / DM_);
    float sq = 0.f;
#pragma unroll
    for (int e = 0; e < 8; ++e) { float d = x[e] - mu; sq += d * d; }
#pragma unroll
    for (int off = 32; off > 0; off >>= 1) sq += __shfl_xor(sq, off);
    float rs = rsqrtf(sq * (1.f / DM_) + 1e-5f);
    int c = l * 8;
    float p = 0.f;
#pragma unroll
    for (int e = 0; e < 8; ++e)
        p += ((x[e] - mu) * rs * gf[c + e] + bf_[c + e]) * wout[c + e];
#pragma unroll
    for (int off = 32; off > 0; off >>= 1) p += __shfl_xor(p, off);
    if (l == 0) out[row] = p + bout[0];
}

// =======================================================================================
extern "C" void kernel_launch(void* const* d_in, const int* in_sizes, int n_in,
                              void* d_out, int out_size, void* d_ws, size_t ws_size,
                              hipStream_t stream) {
    const float* emb   = (const float*)d_in[0];
    const float* W0    = (const float*)d_in[1];
    const float* b0    = (const float*)d_in[2];
    const float* Wq    = (const float*)d_in[3];
    const float* bq    = (const float*)d_in[4];
    const float* Wk    = (const float*)d_in[5];
    const float* bk    = (const float*)d_in[6];
    const float* Wv    = (const float*)d_in[7];
    const float* bv    = (const float*)d_in[8];
    const float* Wo    = (const float*)d_in[9];
    const float* bo    = (const float*)d_in[10];
    const float* ln1s  = (const float*)d_in[11];
    const float* ln1b  = (const float*)d_in[12];
    const float* W1    = (const float*)d_in[13];
    const float* b1    = (const float*)d_in[14];
    const float* W2    = (const float*)d_in[15];
    const float* b2    = (const float*)d_in[16];
    const float* ln2s  = (const float*)d_in[17];
    const float* ln2b  = (const float*)d_in[18];
    const float* lnfs  = (const float*)d_in[19];
    const float* lnfb  = (const float*)d_in[20];
    const float* Wout  = (const float*)d_in[21];
    const float* bout  = (const float*)d_in[22];
    float* out = (float*)d_out;

    char* ws = (char*)d_ws;
    size_t off = 0;
    auto alloc = [&](size_t bytes) -> void* {
        void* p = ws + off;
        off += (bytes + 255) & ~(size_t)255;
        return p;
    };
    u16* xb   = (u16*)alloc((size_t)BS_ * DM_ * 2);    // 32MB  x (bf16 stream)
    u16* qb   = (u16*)alloc((size_t)BS_ * DM_ * 2);    // 32MB
    u16* kb   = (u16*)alloc((size_t)BS_ * DM_ * 2);    // 32MB
    u16* vb   = (u16*)alloc((size_t)BS_ * DM_ * 2);    // 32MB
    float* kvp   = (float*)alloc((size_t)NCH * 64 * 4096 * 4);   // 8MB
    float* ksump = (float*)alloc((size_t)NCH * 64 * 64 * 4);
    u16* kvt  = (u16*)alloc((size_t)64 * 4096 * 2);    // 512KB
    float* ksum = (float*)alloc((size_t)64 * 64 * 4);
    u16* wp   = (u16*)alloc((size_t)4521984 * 2);      // weight pool ~9MB

    u16* ab   = vb;    // attn output (written after vb consumed)
    u16* h1b  = kb;    // 64MB FF hidden = kb+vb regions
    u16* embp = kb;    // 38MB emb bf16 padded = kb+vb regions (dead before QKV)

    u16* W0t  = wp;                          // [512][608]
    u16* Wqkv = wp + 311296;                 // per layer [1536][512]
    u16* Wot  = Wqkv + 2 * 786432;           // per layer [512][512]
    u16* W1t  = Wot + 2 * 262144;            // per layer [1024][512]
    u16* W2t  = W1t + 2 * 524288;            // per layer [512][1024]

    k_tr_all<<<4400, dim3(32, 8), 0, stream>>>(W0, Wq, Wk, Wv, Wo, W1, W2,
                                               W0t, Wqkv, Wot, W1t, W2t);
    k_emb<<<2560, 256, 0, stream>>>(emb, embp);

    // x = emb @ W0 + b0
    k_gemm<0><<<1024, 256, 0, stream>>>(embp, W0t, b0, nullptr, nullptr,
                                        xb, nullptr, nullptr, BS_, DM_, FINP_, 4);

    for (int l = 0; l < 2; ++l) {
        // fused QKV: N=1536, feat(elu+1) on q,k
        k_gemm<1><<<3072, 256, 0, stream>>>(xb, Wqkv + (size_t)l * 786432,
                                            bq + l * 512, bk + l * 512, bv + l * 512,
                                            qb, kb, vb, BS_, 1536, 512, 12);
        k_kv<<<dim3(64, NCH), 256, 0, stream>>>(kb, vb, kvp, ksump);
        k_red<<<dim3(64, 4), 256, 0, stream>>>(kvp, ksump, kvt, ksum);
        k_attn<<<dim3(16, 64), 256, 0, stream>>>(qb, kvt, ksum, ab);
        // x = LN1(x + a@Wo + bo)   (fused: GEMM + resid + LN)
        k_gemm_ln<512><<<512, 512, 0, stream>>>(ab, Wot + (size_t)l * 262144,
                                                bo + l * 512, xb,
                                                ln1s + l * 512, ln1b + l * 512, xb);
        // h = relu(x@W1+b1)
        k_gemm<3><<<2048, 256, 0, stream>>>(xb, W1t + (size_t)l * 524288,
                                            b1 + l * 1024, nullptr, nullptr,
                                            h1b, nullptr, nullptr, BS_, 1024, 512, 8);
        // x = LN2(x + h@W2 + b2)   (fused)
        k_gemm_ln<1024><<<512, 512, 0, stream>>>(h1b, W2t + (size_t)l * 524288,
                                                 b2 + l * 512, xb,
                                                 ln2s + l * 512, ln2b + l * 512, xb);
    }
    k_final<<<8192, 256, 0, stream>>>(xb, lnfs, lnfb, Wout, bout, out);
}

// Round 22
// 587.283 us; speedup vs baseline: 1.1644x; 1.0077x over previous
//
#include <hip/hip_runtime.h>
#include <hip/hip_bf16.h>
#include <math.h>

typedef unsigned short u16;
typedef short s16x8 __attribute__((ext_vector_type(8)));
typedef float f32x4 __attribute__((ext_vector_type(4)));

#define BS_   32768      // B*S
#define SEQ_  4096
#define DM_   512
#define FF_   1024
#define FIN_  586
#define FINP_ 608        // emb K padded to 19*32
#define PADC  136        // epilogue LDS stride (u16), 128-wide tiles
#define PADB  520        // epilogue LDS stride (u16), 512-wide rows
#define NCH   8          // kv S-chunks

__device__ __forceinline__ u16 f2b(float f) {
    __hip_bfloat16 h = __float2bfloat16(f);      // RNE, hw v_cvt on gfx950
    return *reinterpret_cast<u16*>(&h);
}
__device__ __forceinline__ float b2f(u16 h) {
    union { unsigned u; float f; } a; a.u = ((unsigned)h) << 16;
    return a.f;
}

typedef __attribute__((address_space(1))) const unsigned gu32;
typedef __attribute__((address_space(3))) unsigned lu32;
__device__ __forceinline__ void glds16(const void* g, void* l) {
    __builtin_amdgcn_global_load_lds((gu32*)g, (lu32*)l, 16, 0, 0);
}

// ---------------- batched weight transpose + bf16 convert (one launch) ----------------
__device__ __forceinline__ void tr_tile(const float* __restrict__ W, u16* __restrict__ Wt,
                                        int K, int N, int Kpad, int tidx, int ktiles,
                                        float (*t)[33]) {
    int kb = (tidx % ktiles) << 5, nb = (tidx / ktiles) << 5;
    int tx = threadIdx.x, ty = threadIdx.y;          // 32 x 8
#pragma unroll
    for (int j = 0; j < 32; j += 8) {
        int k = kb + ty + j;
        t[ty + j][tx] = (k < K) ? W[(size_t)k * N + nb + tx] : 0.f;
    }
    __syncthreads();
#pragma unroll
    for (int j = 0; j < 32; j += 8) {
        Wt[(size_t)(nb + ty + j) * Kpad + kb + tx] = f2b(t[tx][ty + j]);
    }
}

__global__ void k_tr_all(const float* __restrict__ W0, const float* __restrict__ Wq,
                         const float* __restrict__ Wk, const float* __restrict__ Wv,
                         const float* __restrict__ Wo, const float* __restrict__ W1,
                         const float* __restrict__ W2,
                         u16* __restrict__ W0t, u16* __restrict__ Wqkv,
                         u16* __restrict__ Wot, u16* __restrict__ W1t,
                         u16* __restrict__ W2t) {
    __shared__ float t[32][33];
    int b = blockIdx.x;
    if (b < 304) { tr_tile(W0, W0t, FIN_, DM_, FINP_, b, 19, t); return; }   // 19x16 tiles
    b -= 304;
    int l = b >> 11;              // 2048 tiles per layer
    int r = b & 2047;
    if (r < 768) {                // q,k,v : 256 tiles each
        int sel = r >> 8, ti = r & 255;
        const float* src = sel == 0 ? Wq : (sel == 1 ? Wk : Wv);
        tr_tile(src + (size_t)l * 262144, Wqkv + (size_t)l * 786432 + (size_t)sel * 262144,
                512, 512, 512, ti, 16, t);
    } else if (r < 1024) {
        tr_tile(Wo + (size_t)l * 262144, Wot + (size_t)l * 262144, 512, 512, 512, r - 768, 16, t);
    } else if (r < 1536) {
        tr_tile(W1 + (size_t)l * 524288, W1t + (size_t)l * 524288, 512, 1024, 512, r - 1024, 16, t);
    } else {
        tr_tile(W2 + (size_t)l * 524288, W2t + (size_t)l * 524288, 1024, 512, 1024, r - 1536, 32, t);
    }
}

// ---------------- embeddings -> bf16 padded [BS][608] ---------------------------------
__global__ __launch_bounds__(256)
void k_emb(const float* __restrict__ E, u16* __restrict__ Ep) {
    const int total8 = BS_ * (FINP_ / 8);
    for (int i = blockIdx.x * 256 + threadIdx.x; i < total8; i += gridDim.x * 256) {
        int rr = i / (FINP_ / 8), c = (i % (FINP_ / 8)) * 8;
        const float* rp = E + (size_t)rr * FIN_ + c;
        s16x8 o;
#pragma unroll
        for (int e = 0; e < 8; ++e) {
            float v = (c + e < FIN_) ? rp[e] : 0.f;
            o[e] = (short)f2b(v);
        }
        *(s16x8*)(Ep + (size_t)rr * FINP_ + c) = o;
    }
}

// ---------------- MFMA GEMM: 128x128, BK=32, dbuf, 32KB LDS, 4 blocks/CU --------------
// 8-slot swizzle: stage source chunk = (tid&3)^((srow>>1)&3); read = lg^((lr>>1)&3).
// EPI: 0 = bias only, 1 = QKV split (feat on q,k), 3 = relu
template<int EPI>
__global__ __launch_bounds__(256, 4)
void k_gemm(const u16* __restrict__ A, const u16* __restrict__ Bt,
            const float* __restrict__ bias0, const float* __restrict__ bias1,
            const float* __restrict__ bias2,
            u16* __restrict__ out0, u16* __restrict__ out1, u16* __restrict__ out2,
            int M, int N, int K, int NT) {
    __shared__ __align__(16) u16 smem[16384];      // 32 KB; sC epilogue unions in
    u16* sC = smem;

    const int nwg = gridDim.x;
    const int cpx = nwg >> 3;                      // nwg % 8 == 0 for all launches here
    const int wg = (blockIdx.x & 7) * cpx + (blockIdx.x >> 3);
    const int mt = wg / NT, nt = wg - mt * NT;
    const int m0 = mt << 7, n0 = nt << 7;
    const int tid = threadIdx.x;
    const int w = tid >> 6, l = tid & 63;
    const int wm = (w >> 1) << 6, wn = (w & 1) << 6;
    const int lr = l & 15, lg = l >> 4;

    const int srow = tid >> 2;                     // 0..63
    const int swz = (((tid & 3) ^ ((srow >> 1) & 3)) & 3) << 3;   // 8-slot swizzle source
    const u16* Ap = A + (size_t)(m0 + srow) * K + swz;
    const u16* Bp = Bt + (size_t)(n0 + srow) * K + swz;

    auto stage = [&](int d, int tt) {
        const size_t ko = (size_t)tt << 5;
        u16* da = smem + d * 4096 + tid * 8;
        u16* db = smem + 8192 + d * 4096 + tid * 8;
        glds16(Ap + ko, da);
        glds16(Ap + ko + (size_t)64 * K, da + 2048);
        glds16(Bp + ko, db);
        glds16(Bp + ko + (size_t)64 * K, db + 2048);
    };

    const int axk = ((lg ^ ((lr >> 1) & 3)) & 3) << 3;   // read-side swizzle

    f32x4 acc[4][4] = {};
    const int ntile = K >> 5;

    stage(0, 0);
    __syncthreads();

    for (int t = 0; t < ntile; ++t) {
        const int d = t & 1;
        if (t + 1 < ntile) stage(d ^ 1, t + 1);
        const u16* sA = smem + d * 4096;
        const u16* sB = smem + 8192 + d * 4096;
        s16x8 af[4], bfr[4];
#pragma unroll
        for (int i = 0; i < 4; ++i) af[i] = *(const s16x8*)(sA + (wm + i * 16 + lr) * 32 + axk);
#pragma unroll
        for (int j = 0; j < 4; ++j) bfr[j] = *(const s16x8*)(sB + (wn + j * 16 + lr) * 32 + axk);
        __builtin_amdgcn_s_setprio(1);
#pragma unroll
        for (int i = 0; i < 4; ++i)
#pragma unroll
            for (int j = 0; j < 4; ++j)
                acc[i][j] = __builtin_amdgcn_mfma_f32_16x16x32_bf16(af[i], bfr[j], acc[i][j], 0, 0, 0);
        __builtin_amdgcn_s_setprio(0);
        __syncthreads();
    }

    const int seg = (EPI == 1) ? (n0 >> 9) : 0;
    const float* bias = (EPI == 1) ? (seg == 0 ? bias0 : (seg == 1 ? bias1 : bias2)) : bias0;
    u16* dst = (EPI == 1) ? (seg == 0 ? out0 : (seg == 1 ? out1 : out2)) : out0;
    const int ldo = (EPI == 1) ? 512 : N;
    const int ncol0 = (EPI == 1) ? (n0 & 511) : n0;

#pragma unroll
    for (int pass = 0; pass < 2; ++pass) {
        if ((w >> 1) == pass) {
#pragma unroll
            for (int j = 0; j < 4; ++j) {
                const int col = wn + j * 16 + lr;
                const float bv = bias[ncol0 + col];
#pragma unroll
                for (int i = 0; i < 4; ++i)
#pragma unroll
                    for (int r = 0; r < 4; ++r) {
                        const int row = i * 16 + (lg << 2) + r;
                        sC[row * PADC + col] = f2b(acc[i][j][r] + bv);
                    }
            }
        }
        __syncthreads();
        const int rbase = m0 + (pass << 6);
#pragma unroll
        for (int t = 0; t < 4; ++t) {
            const int idx = t * 256 + tid;
            const int row = idx >> 4;
            const int c8 = (idx & 15) << 3;
            s16x8 v8 = *(const s16x8*)(sC + row * PADC + c8);
            size_t gaddr = (size_t)(rbase + row) * ldo + ncol0 + c8;
            s16x8 o = v8;
            if constexpr (EPI == 1) {
                if (seg < 2) {
#pragma unroll
                    for (int e = 0; e < 8; ++e) {
                        float v = b2f((u16)v8[e]);
                        v = (v > 0.f) ? v + 1.f : __expf(v);   // elu+1
                        o[e] = (short)f2b(v);
                    }
                }
            } else if constexpr (EPI == 3) {
#pragma unroll
                for (int e = 0; e < 8; ++e)
                    o[e] = (short)f2b(fmaxf(b2f((u16)v8[e]), 0.f));
            }
            *(s16x8*)(dst + gaddr) = o;
        }
        __syncthreads();
    }
}

// ---------------- row-tile GEMM + residual + LayerNorm fused --------------------------
template<int K>
__global__ __launch_bounds__(512, 4)
void k_gemm_ln(const u16* __restrict__ A, const u16* __restrict__ Bt,
               const float* __restrict__ bias, const u16* __restrict__ resid,
               const float* __restrict__ g, const float* __restrict__ be,
               u16* __restrict__ xb) {
    __shared__ __align__(16) u16 smem[36864];      // 72 KB; sC[64][PADB] unions in
    u16* sC = smem;

    const int nwg = gridDim.x;
    const int cpx = nwg >> 3;
    const int wg = (blockIdx.x & 7) * cpx + (blockIdx.x >> 3);
    const int m0 = wg << 6;                        // 64 rows per block, N = 512 full
    const int tid = threadIdx.x;
    const int w = tid >> 6, l = tid & 63;
    const int wn = w << 6;
    const int lr = l & 15, lg = l >> 4;

    const int srow = tid >> 2;                     // 0..127
    const int swz = (((tid & 3) ^ ((srow >> 1) & 3)) & 3) << 3;
    const u16* ApA = A + (size_t)(m0 + (srow & 63)) * K + ((((tid & 3) ^ (((srow & 63) >> 1) & 3)) & 3) << 3);
    const u16* BpB = Bt + (size_t)srow * K + swz;

    auto stage = [&](int d, int tt) {
        const size_t ko = (size_t)tt << 5;
        if (tid < 256) glds16(ApA + ko, smem + d * 2048 + tid * 8);
#pragma unroll
        for (int c = 0; c < 4; ++c)
            glds16(BpB + ko + (size_t)(c * 128) * K,
                   smem + 4096 + d * 16384 + c * 4096 + tid * 8);
    };

    const int axk = ((lg ^ ((lr >> 1) & 3)) & 3) << 3;

    f32x4 acc[4][4] = {};
    const int ntile = K >> 5;

    stage(0, 0);
    __syncthreads();

    for (int t = 0; t < ntile; ++t) {
        const int d = t & 1;
        if (t + 1 < ntile) stage(d ^ 1, t + 1);
        const u16* sA = smem + d * 2048;
        const u16* sB = smem + 4096 + d * 16384 + wn * 32;
        s16x8 af[4], bfr[4];
#pragma unroll
        for (int i = 0; i < 4; ++i) af[i] = *(const s16x8*)(sA + (i * 16 + lr) * 32 + axk);
#pragma unroll
        for (int j = 0; j < 4; ++j) bfr[j] = *(const s16x8*)(sB + (j * 16 + lr) * 32 + axk);
        __builtin_amdgcn_s_setprio(1);
#pragma unroll
        for (int i = 0; i < 4; ++i)
#pragma unroll
            for (int j = 0; j < 4; ++j)
                acc[i][j] = __builtin_amdgcn_mfma_f32_16x16x32_bf16(af[i], bfr[j], acc[i][j], 0, 0, 0);
        __builtin_amdgcn_s_setprio(0);
        __syncthreads();
    }

#pragma unroll
    for (int j = 0; j < 4; ++j) {
        const int col = wn + j * 16 + lr;
        const float bv = bias[col];
#pragma unroll
        for (int i = 0; i < 4; ++i)
#pragma unroll
            for (int r = 0; r < 4; ++r) {
                const int row = i * 16 + (lg << 2) + r;     // 0..63
                sC[row * PADB + col] = f2b(acc[i][j][r] + bv);
            }
    }
    __syncthreads();

#pragma unroll
    for (int it = 0; it < 8; ++it) {
        const int row = it * 8 + w;                 // 0..63
        s16x8 cv = *(const s16x8*)(sC + row * PADB + l * 8);
        s16x8 rv = *(const s16x8*)(resid + (size_t)(m0 + row) * DM_ + l * 8);
        float x[8];
#pragma unroll
        for (int e = 0; e < 8; ++e) x[e] = b2f((u16)cv[e]) + b2f((u16)rv[e]);
        float sum = 0.f;
#pragma unroll
        for (int e = 0; e < 8; ++e) sum += x[e];
#pragma unroll
        for (int off = 32; off > 0; off >>= 1) sum += __shfl_xor(sum, off);
        float mu = sum * (1.f / DM_);
        float sq = 0.f;
#pragma unroll
        for (int e = 0; e < 8; ++e) { float d = x[e] - mu; sq += d * d; }
#pragma unroll
        for (int off = 32; off > 0; off >>= 1) sq += __shfl_xor(sq, off);
        float rs = rsqrtf(sq * (1.f / DM_) + 1e-5f);
        const int c = l * 8;
        const f32x4* gp = (const f32x4*)(g + c);
        const f32x4* bp = (const f32x4*)(be + c);
        f32x4 g0 = gp[0], g1 = gp[1], e0 = bp[0], e1 = bp[1];
        s16x8 pk;
#pragma unroll
        for (int e = 0; e < 4; ++e) pk[e] = (short)f2b((x[e] - mu) * rs * g0[e] + e0[e]);
#pragma unroll
        for (int e = 0; e < 4; ++e) pk[4 + e] = (short)f2b((x[4 + e] - mu) * rs * g1[e] + e1[e]);
        *(s16x8*)(xb + (size_t)(m0 + row) * DM_ + c) = pk;
    }
}

// ---------------- kv einsum partials ---------------------------------------------------
__global__ __launch_bounds__(256)
void k_kv(const u16* __restrict__ kb_, const u16* __restrict__ vb_,
          float* __restrict__ kvp, float* __restrict__ ksump) {
    __shared__ float sk[64 * 68], sv[64 * 68];
    int bh = blockIdx.x, b = bh >> 3, h = bh & 7;
    int ch = blockIdx.y;
    int tid = threadIdx.x;
    int d0 = (tid & 15) << 2, m0 = (tid >> 4) << 2;
    float acc[4][4] = {};
    float ks[4] = {0.f, 0.f, 0.f, 0.f};
    size_t gbase = ((size_t)b * SEQ_ + (size_t)ch * (SEQ_ / NCH)) * DM_ + h * 64;

    for (int st = 0; st < SEQ_ / NCH; st += 64) {
#pragma unroll
        for (int i = 0; i < 2; ++i) {
            int li = tid + (i << 8);
            int r = li >> 3, c8 = (li & 7) << 3;
            s16x8 kv_ = *(const s16x8*)(kb_ + gbase + (size_t)(st + r) * DM_ + c8);
            s16x8 vv_ = *(const s16x8*)(vb_ + gbase + (size_t)(st + r) * DM_ + c8);
#pragma unroll
            for (int e = 0; e < 8; ++e) {
                sk[r * 68 + c8 + e] = b2f((u16)kv_[e]);
                sv[r * 68 + c8 + e] = b2f((u16)vv_[e]);
            }
        }
        __syncthreads();
        for (int s = 0; s < 64; ++s) {
            f32x4 kd = *(const f32x4*)(sk + s * 68 + d0);
            f32x4 vm = *(const f32x4*)(sv + s * 68 + m0);
#pragma unroll
            for (int i = 0; i < 4; ++i)
#pragma unroll
                for (int j = 0; j < 4; ++j) acc[i][j] += kd[i] * vm[j];
            if ((tid >> 4) == 0) { ks[0] += kd[0]; ks[1] += kd[1]; ks[2] += kd[2]; ks[3] += kd[3]; }
        }
        __syncthreads();
    }
    float* kvo = kvp + ((size_t)ch * 64 + bh) * 4096;
#pragma unroll
    for (int i = 0; i < 4; ++i)
#pragma unroll
        for (int j = 0; j < 4; ++j) kvo[(d0 + i) * 64 + m0 + j] = acc[i][j];
    if ((tid >> 4) == 0) {
        float* kso = ksump + ((size_t)ch * 64 + bh) * 64;
#pragma unroll
        for (int e = 0; e < 4; ++e) kso[d0 + e] = ks[e];
    }
}

// ---------------- reduce partials once: kvt bf16 [bh][m][d swizzled] + ksum f32 -------
__global__ __launch_bounds__(256)
void k_red(const float* __restrict__ kvp, const float* __restrict__ ksump,
           u16* __restrict__ kvt, float* __restrict__ ksum) {
    int bh = blockIdx.x, q = blockIdx.y;           // q in 0..3
    int tid = threadIdx.x;
#pragma unroll
    for (int p = 0; p < 4; ++p) {
        int i = (q * 4 + p) * 256 + tid;           // i = d*64 + m
        float v = 0.f;
#pragma unroll
        for (int c = 0; c < NCH; ++c) v += kvp[((size_t)c * 64 + bh) * 4096 + i];
        int d = i >> 6, m = i & 63;
        int slot = ((d >> 3) ^ (m & 7)) & 7;
        kvt[(size_t)bh * 4096 + m * 64 + slot * 8 + (d & 7)] = f2b(v);
    }
    if (q == 0 && tid < 64) {
        float v = 0.f;
#pragma unroll
        for (int c = 0; c < NCH; ++c) v += ksump[((size_t)c * 64 + bh) * 64 + tid];
        ksum[bh * 64 + tid] = v;
    }
}

// ---------------- attention apply via MFMA: a = (q . kv) * z --------------------------
__global__ __launch_bounds__(256)
void k_attn(const u16* __restrict__ qb_, const u16* __restrict__ kvt,
            const float* __restrict__ ksum, u16* __restrict__ ab_) {
    __shared__ __align__(16) u16 qs[256 * 64];     // 32KB (reused as output bounce)
    __shared__ __align__(16) u16 skv[64 * 64];     // 8KB
    __shared__ float sden[256];
    __shared__ float sks[64];
    const int tid = threadIdx.x;
    const int bh = blockIdx.y, b = bh >> 3, h = bh & 7;
    const int s0 = blockIdx.x << 8;                // 256 rows
    const int w = tid >> 6, l = tid & 63;
    const int lr = l & 15, lg = l >> 4;

    {
        const int srw = tid >> 3, ch = tid & 7;
        const int scol = ((ch ^ (srw & 7)) & 7) << 3;
        const u16* qsrc = qb_ + ((size_t)b * SEQ_ + s0 + srw) * DM_ + h * 64 + scol;
#pragma unroll
        for (int p = 0; p < 8; ++p)
            glds16(qsrc + (size_t)(p * 32) * DM_, qs + p * 2048 + tid * 8);
#pragma unroll
        for (int p = 0; p < 2; ++p)
            glds16(kvt + (size_t)bh * 4096 + p * 2048 + tid * 8, skv + p * 2048 + tid * 8);
    }
    if (tid < 64) sks[tid] = ksum[bh * 64 + tid];
    __syncthreads();

    {
        const int row = (w << 6) + l;
        float den = 0.f;
#pragma unroll
        for (int c = 0; c < 8; ++c) {
            s16x8 qv = *(const s16x8*)(qs + row * 64 + (((c ^ (row & 7)) & 7) << 3));
#pragma unroll
            for (int e = 0; e < 8; ++e) den += b2f((u16)qv[e]) * sks[c * 8 + e];
        }
        sden[row] = 1.f / (den + 1e-6f);
    }
    __syncthreads();

    f32x4 acc[4][4] = {};
#pragma unroll
    for (int kh = 0; kh < 2; ++kh) {
        const int c = kh * 4 + lg;
        s16x8 bfr[4];
#pragma unroll
        for (int j = 0; j < 4; ++j) {
            const int mm = j * 16 + lr;
            bfr[j] = *(const s16x8*)(skv + mm * 64 + (((c ^ (mm & 7)) & 7) << 3));
        }
#pragma unroll
        for (int i = 0; i < 4; ++i) {
            const int rr = (w << 6) + i * 16 + lr;
            s16x8 af = *(const s16x8*)(qs + rr * 64 + (((c ^ (rr & 7)) & 7) << 3));
#pragma unroll
            for (int j = 0; j < 4; ++j)
                acc[i][j] = __builtin_amdgcn_mfma_f32_16x16x32_bf16(af, bfr[j], acc[i][j], 0, 0, 0);
        }
    }
    __syncthreads();                               // all qs reads done; reuse as bounce

#pragma unroll
    for (int i = 0; i < 4; ++i) {
#pragma unroll
        for (int r = 0; r < 4; ++r) {
            const int row = (w << 6) + i * 16 + (lg << 2) + r;
            const float z = sden[row];
#pragma unroll
            for (int j = 0; j < 4; ++j)
                qs[row * 64 + j * 16 + lr] = f2b(acc[i][j][r] * z);
        }
    }
    __syncthreads();
    {
        const int srw = tid >> 3, ch = tid & 7;
        u16* odst = ab_ + ((size_t)b * SEQ_ + s0 + srw) * DM_ + h * 64 + ch * 8;
#pragma unroll
        for (int p = 0; p < 8; ++p)
            *(s16x8*)(odst + (size_t)(p * 32) * DM_) = *(const s16x8*)(qs + p * 2048 + tid * 8);
    }
}

// ---------------- final LN + Wout dot (bf16 in) ----------------------------------------
__global__ __launch_bounds__(256)
void k_final(const u16* __restrict__ in, const float* __restrict__ gf,
             const float* __restrict__ bf_, const float* __restrict__ wout,
             const float* __restrict__ bout, float* __restrict__ out) {
    int row = blockIdx.x * 4 + (threadIdx.x >> 6);
    int l = threadIdx.x & 63;
    s16x8 raw = *(const s16x8*)(in + (size_t)row * DM_ + l * 8);
    float x[8];
#pragma unroll
    for (int e = 0; e < 8; ++e) x[e] = b2f((u16)raw[e]);
    float sum = 0.f;
#pragma unroll
    for (int e = 0; e < 8; ++e) sum += x[e];
#pragma unroll
    for (int off = 32; off > 0; off >>= 1) sum += __shfl_xor(sum, off);
    float mu = sum * (1.f / DM_);
    float sq = 0.f;
#pragma unroll
    for (int e = 0; e < 8; ++e) { float d = x[e] - mu; sq += d * d; }
#pragma unroll
    for (int off = 32; off > 0; off >>= 1) sq += __shfl_xor(sq, off);
    float rs = rsqrtf(sq * (1.f / DM_) + 1e-5f);
    int c = l * 8;
    float p = 0.f;
#pragma unroll
    for (int e = 0; e < 8; ++e)
        p += ((x[e] - mu) * rs * gf[c + e] + bf_[c + e]) * wout[c + e];
#pragma unroll
    for (int off = 32; off > 0; off >>= 1) p += __shfl_xor(p, off);
    if (l == 0) out[row] = p + bout[0];
}

// =======================================================================================
extern "C" void kernel_launch(void* const* d_in, const int* in_sizes, int n_in,
                              void* d_out, int out_size, void* d_ws, size_t ws_size,
                              hipStream_t stream) {
    const float* emb   = (const float*)d_in[0];
    const float* W0    = (const float*)d_in[1];
    const float* b0    = (const float*)d_in[2];
    const float* Wq    = (const float*)d_in[3];
    const float* bq    = (const float*)d_in[4];
    const float* Wk    = (const float*)d_in[5];
    const float* bk    = (const float*)d_in[6];
    const float* Wv    = (const float*)d_in[7];
    const float* bv    = (const float*)d_in[8];
    const float* Wo    = (const float*)d_in[9];
    const float* bo    = (const float*)d_in[10];
    const float* ln1s  = (const float*)d_in[11];
    const float* ln1b  = (const float*)d_in[12];
    const float* W1    = (const float*)d_in[13];
    const float* b1    = (const float*)d_in[14];
    const float* W2    = (const float*)d_in[15];
    const float* b2    = (const float*)d_in[16];
    const float* ln2s  = (const float*)d_in[17];
    const float* ln2b  = (const float*)d_in[18];
    const float* lnfs  = (const float*)d_in[19];
    const float* lnfb  = (const float*)d_in[20];
    const float* Wout  = (const float*)d_in[21];
    const float* bout  = (const float*)d_in[22];
    float* out = (float*)d_out;

    char* ws = (char*)d_ws;
    size_t off = 0;
    auto alloc = [&](size_t bytes) -> void* {
        void* p = ws + off;
        off += (bytes + 255) & ~(size_t)255;
        return p;
    };
    u16* xb   = (u16*)alloc((size_t)BS_ * DM_ * 2);    // 32MB  x (bf16 stream)
    u16* qb   = (u16*)alloc((size_t)BS_ * DM_ * 2);    // 32MB
    u16* kb   = (u16*)alloc((size_t)BS_ * DM_ * 2);    // 32MB
    u16* vb   = (u16*)alloc((size_t)BS_ * DM_ * 2);    // 32MB
    float* kvp   = (float*)alloc((size_t)NCH * 64 * 4096 * 4);   // 8MB
    float* ksump = (float*)alloc((size_t)NCH * 64 * 64 * 4);
    u16* kvt  = (u16*)alloc((size_t)64 * 4096 * 2);    // 512KB
    float* ksum = (float*)alloc((size_t)64 * 64 * 4);
    u16* wp   = (u16*)alloc((size_t)4521984 * 2);      // weight pool ~9MB

    u16* ab   = vb;    // attn output (written after vb consumed)
    u16* h1b  = kb;    // 64MB FF hidden = kb+vb regions
    u16* embp = kb;    // 38MB emb bf16 padded = kb+vb regions (dead before QKV)

    u16* W0t  = wp;                          // [512][608]
    u16* Wqkv = wp + 311296;                 // per layer [1536][512]
    u16* Wot  = Wqkv + 2 * 786432;           // per layer [512][512]
    u16* W1t  = Wot + 2 * 262144;            // per layer [1024][512]
    u16* W2t  = W1t + 2 * 524288;            // per layer [512][1024]

    k_tr_all<<<4400, dim3(32, 8), 0, stream>>>(W0, Wq, Wk, Wv, Wo, W1, W2,
                                               W0t, Wqkv, Wot, W1t, W2t);
    k_emb<<<2560, 256, 0, stream>>>(emb, embp);

    // x = emb @ W0 + b0
    k_gemm<0><<<1024, 256, 0, stream>>>(embp, W0t, b0, nullptr, nullptr,
                                        xb, nullptr, nullptr, BS_, DM_, FINP_, 4);

    for (int l = 0; l < 2; ++l) {
        // fused QKV: N=1536, feat(elu+1) on q,k
        k_gemm<1><<<3072, 256, 0, stream>>>(xb, Wqkv + (size_t)l * 786432,
                                            bq + l * 512, bk + l * 512, bv + l * 512,
                                            qb, kb, vb, BS_, 1536, 512, 12);
        k_kv<<<dim3(64, NCH), 256, 0, stream>>>(kb, vb, kvp, ksump);
        k_red<<<dim3(64, 4), 256, 0, stream>>>(kvp, ksump, kvt, ksum);
        k_attn<<<dim3(16, 64), 256, 0, stream>>>(qb, kvt, ksum, ab);
        // x = LN1(x + a@Wo + bo)   (fused: GEMM + resid + LN)
        k_gemm_ln<512><<<512, 512, 0, stream>>>(ab, Wot + (size_t)l * 262144,
                                                bo + l * 512, xb,
                                                ln1s + l * 512, ln1b + l * 512, xb);
        // h = relu(x@W1+b1)
        k_gemm<3><<<2048, 256, 0, stream>>>(xb, W1t + (size_t)l * 524288,
                                            b1 + l * 1024, nullptr, nullptr,
                                            h1b, nullptr, nullptr, BS_, 1024, 512, 8);
        // x = LN2(x + h@W2 + b2)   (fused)
        k_gemm_ln<1024><<<512, 512, 0, stream>>>(h1b, W2t + (size_t)l * 524288,
                                                 b2 + l * 512, xb,
                                                 ln2s + l * 512, ln2b + l * 512, xb);
    }
    k_final<<<8192, 256, 0, stream>>>(xb, lnfs, lnfb, Wout, bout, out);
}